// Round 8
// baseline (218.900 us; speedup 1.0000x reference)
//
#include <hip/hip_runtime.h>
#include <cstdint>

// ---------------- problem constants ----------------
// features [8,2048,256] f32; Wq/Wk/Wv [256,512]; W2 [512,256]; b2 [256]
// out [8,2048,256] f32
#define NBATCH 8
#define NSEQ   2048
#define NROWS  16384

typedef __attribute__((ext_vector_type(4))) float  f32x4;
typedef __attribute__((ext_vector_type(8))) short  short8;
typedef __attribute__((ext_vector_type(8))) __bf16 bf16x8;
typedef __attribute__((ext_vector_type(8))) _Float16 h8;

// ---------------- workspace layout (bytes) ----------------
// Xb/Wall: row-granule-swizzled bf16 (16B granule index ^= row&7 within row)
// Q  : TILED [t 128][ck 8][r 128][128B], granules stored[p]=true[p^(r&7)]
//      (Q is glds-staged into LDS -> needs the bank swizzle)
// K  : TILED [t 128][ck 8][r 128][128B], granules LINEAR (read direct from L2)
// Vt : TILED [b 8][ktv 32][c 512][128B], granules LINEAR (read direct from L2)
// W2t: LINEAR [256 d][512 c] bf16 (read direct from global in fc2)
// S/P: TILED  [z][rg 32][ck 32][r64 64][128B]; f16 S (linear granules) is
//      overwritten in place by bf16 P (granules stored[p]=true[p^(r&7)],
//      since P IS glds-staged by pv)
#define XB_OFF   0ul          // 8388608
#define WALL_OFF 8388608ul    // 786432 (Wq^T*scale | Wk^T | Wv^T)
#define Q_OFF    9175040ul    // 16777216 (pre-scaled by log2e/sqrt(512))
#define K_OFF    25952256ul   // 16777216
#define VT_OFF   42729472ul   // 16777216
#define W2T_OFF  59506688ul   // 262144
#define S_OFF    59768832ul   // nb * 8388608

#define SCALE_Q 0.063758746f  // (1/sqrt(512)) * log2(e)

__device__ __forceinline__ unsigned short f2bf(float f) {
  unsigned u = __builtin_bit_cast(unsigned, f);
  return (unsigned short)((u + 0x7fffu + ((u >> 16) & 1u)) >> 16);  // RNE
}

__device__ __forceinline__ f32x4 mfma16(short8 a, short8 b, f32x4 c) {
  return __builtin_amdgcn_mfma_f32_16x16x32_bf16(
      __builtin_bit_cast(bf16x8, a), __builtin_bit_cast(bf16x8, b), c, 0, 0, 0);
}

__device__ __forceinline__ void glds16(const void* g, void* l) {
  __builtin_amdgcn_global_load_lds(
      (const __attribute__((address_space(1))) void*)g,
      (__attribute__((address_space(3))) void*)l, 16, 0, 0);
}

#define BAR_SYNC()                     \
  {                                    \
    __builtin_amdgcn_sched_barrier(0); \
    __builtin_amdgcn_s_barrier();      \
    __builtin_amdgcn_sched_barrier(0); \
  }
#define BAR_LGKM()                                           \
  {                                                          \
    asm volatile("s_waitcnt lgkmcnt(0)" ::: "memory");       \
    __builtin_amdgcn_sched_barrier(0);                       \
    __builtin_amdgcn_s_barrier();                            \
    __builtin_amdgcn_sched_barrier(0);                       \
  }
#define WAITV(N)                                                  \
  {                                                               \
    asm volatile("s_waitcnt vmcnt(" #N ")" ::: "memory");         \
    __builtin_amdgcn_sched_barrier(0);                            \
  }

// ============================================================
// prep: bf16 conversions + transposes + swizzled layouts
// ============================================================
__global__ __launch_bounds__(256, 4) void prep_kernel(
    const float* __restrict__ feat, const float* __restrict__ Wq,
    const float* __restrict__ Wk, const float* __restrict__ Wv,
    const float* __restrict__ W2, char* __restrict__ ws) {
  int tid = blockIdx.x * 256 + threadIdx.x;
  if (tid < 524288) {  // Xb: 8-elem chunks
    int r = tid >> 5, co = (tid & 31) * 8;
    const float* src = feat + (size_t)r * 256 + co;
    short8 v;
#pragma unroll
    for (int i = 0; i < 8; ++i) v[i] = (short)f2bf(src[i]);
    unsigned short* Xb = (unsigned short*)(ws + XB_OFF);
    *(short8*)(Xb + (size_t)r * 256 + (co ^ ((r & 7) << 3))) = v;
  } else if (tid < 917504) {  // Wall[m][d] = W*[d][m] (scale folded into Wq)
    int t2 = tid - 524288;
    int m = t2 >> 8, d = t2 & 255;
    int wsel = m >> 9, mm = m & 511;
    const float* W = (wsel == 0) ? Wq : ((wsel == 1) ? Wk : Wv);
    float v = W[(size_t)d * 512 + mm];
    if (wsel == 0) v *= SCALE_Q;
    unsigned short* Wall = (unsigned short*)(ws + WALL_OFF);
    Wall[(size_t)m * 256 + (d ^ ((m & 7) << 3))] = f2bf(v);
  } else {  // W2t[d][c] = W2[c][d]  (LINEAR)
    int t3 = tid - 917504;
    int d = t3 >> 9, c = t3 & 511;
    unsigned short* W2t = (unsigned short*)(ws + W2T_OFF);
    W2t[(size_t)d * 512 + c] = f2bf(W2[(size_t)c * 256 + d]);
  }
}

// ============================================================
// proj: [16384,256] @ [256, 512*3] -> Q (swz), K (linear), Vt (linear)
// 1536 blocks (XCD-chunked swizzle), 4 waves, 128x128 tile, BK=64 dbuf
// ============================================================
__global__ __launch_bounds__(256, 2) void proj_kernel(char* __restrict__ ws) {
  __shared__ char smem[65536];  // A dbuf 2x16KB @0, B dbuf 2x16KB @32768
  const int tid = threadIdx.x;
  const int l = tid & 63, w = tid >> 6;
  const int g = l >> 4, m16 = l & 15;
  const int orig = blockIdx.x;
  const int wgid = (orig & 7) * 192 + (orig >> 3);  // 1536%8==0, bijective
  const int nt = wgid % 12, mtb = wgid / 12;
  const char* XbT = ws + XB_OFF + (size_t)mtb * 65536;     // [128 r][512B]
  const char* WallT = ws + WALL_OFF + (size_t)nt * 65536;  // [128 r][512B]

  auto stage = [&](int buf, int kt) {
#pragma unroll
    for (int j = 0; j < 4; ++j) {
      int idx = j * 256 + tid;  // 0..1023: r=idx>>3, p=idx&7
      int r = idx >> 3, p = idx & 7;
      glds16(XbT + r * 512 + kt * 128 + p * 16, smem + buf * 16384 + idx * 16);
      glds16(WallT + r * 512 + kt * 128 + p * 16,
             smem + 32768 + buf * 16384 + idx * 16);
    }
  };

  const int mr = (w >> 1) * 64, nr = (w & 1) * 64;
  const int fxor = (m16 & 7) << 4;
  const f32x4 fz = {0.f, 0.f, 0.f, 0.f};
  f32x4 acc[4][4];
#pragma unroll
  for (int i = 0; i < 4; ++i)
#pragma unroll
    for (int j = 0; j < 4; ++j) acc[i][j] = fz;

  stage(0, 0);
  int cur = 0;
#pragma unroll 1
  for (int kt = 0; kt < 4; ++kt) {
    if (kt < 3) {
      stage(cur ^ 1, kt + 1);
      WAITV(8);
    } else {
      WAITV(0);
    }
    BAR_SYNC();
    const char* Ab = smem + cur * 16384;
    const char* Bb = smem + 32768 + cur * 16384;
#pragma unroll
    for (int ks = 0; ks < 2; ++ks) {
      int off = (16 * g + 64 * ks) ^ fxor;
      short8 af[4], bf[4];
#pragma unroll
      for (int i = 0; i < 4; ++i)
        af[i] = *(const short8*)(Ab + (mr + i * 16 + m16) * 128 + off);
#pragma unroll
      for (int i = 0; i < 4; ++i)
        bf[i] = *(const short8*)(Bb + (nr + i * 16 + m16) * 128 + off);
#pragma unroll
      for (int mi = 0; mi < 4; ++mi)
#pragma unroll
        for (int ni = 0; ni < 4; ++ni)
          acc[mi][ni] = mfma16(af[mi], bf[ni], acc[mi][ni]);
    }
    BAR_LGKM();
    cur ^= 1;
  }

  // ---- epilogue ----
  const int colg = nt * 128 + nr;
  const int tcat = colg >> 9;       // 0=Q 1=K 2=V
  const int cin_base = colg & 511;  // col within tensor
  char* wbuf = smem + w * 2048;     // per-wave [16][128B]
  if (tcat < 2) {
    char* dst = ws + (tcat == 0 ? Q_OFF : K_OFF) +
                ((size_t)(mtb * 8 + (cin_base >> 6))) * 16384;
#pragma unroll
    for (int mi = 0; mi < 4; ++mi) {
#pragma unroll
      for (int ni = 0; ni < 4; ++ni)
#pragma unroll
        for (int j = 0; j < 4; ++j) {
          int r = g * 4 + j, c = ni * 16 + m16;
          *(unsigned short*)(wbuf + r * 128 + ((2 * c) ^ ((r & 7) << 4))) =
              f2bf(acc[mi][ni][j]);
        }
      asm volatile("s_waitcnt lgkmcnt(0)" ::: "memory");
      __builtin_amdgcn_sched_barrier(0);
#pragma unroll
      for (int s = 0; s < 2; ++s) {
        int cid = l + 64 * s;
        int r2 = cid >> 3, gi = cid & 7;
        // Q keeps LDS-swizzled granules; K stored LINEAR (direct-L2 reads)
        int slot = (tcat == 0) ? gi : (gi ^ (r2 & 7));
        short8 v = *(const short8*)(wbuf + r2 * 128 + slot * 16);
        int rt = mr + mi * 16 + r2;  // row in tile
        *(short8*)(dst + (size_t)rt * 128 + gi * 16) = v;
      }
    }
  } else {
    // V: gather column l per mi into registers, write each 128B row ONCE
    short8 grans[8];
#pragma unroll
    for (int mi = 0; mi < 4; ++mi) {
#pragma unroll
      for (int ni = 0; ni < 4; ++ni)
#pragma unroll
        for (int j = 0; j < 4; ++j) {
          int r = g * 4 + j, c = ni * 16 + m16;
          *(unsigned short*)(wbuf + r * 128 + ((2 * c) ^ ((r & 7) << 4))) =
              f2bf(acc[mi][ni][j]);
        }
      asm volatile("s_waitcnt lgkmcnt(0)" ::: "memory");
      __builtin_amdgcn_sched_barrier(0);
      unsigned short vals[16];
#pragma unroll
      for (int r2 = 0; r2 < 16; ++r2)
        vals[r2] = *(const unsigned short*)(wbuf + r2 * 128 +
                                            ((2 * l) ^ ((r2 & 7) << 4)));
      short8 v0, v1;
#pragma unroll
      for (int i2 = 0; i2 < 8; ++i2) {
        v0[i2] = (short)vals[i2];
        v1[i2] = (short)vals[8 + i2];
      }
      grans[2 * mi] = v0;
      grans[2 * mi + 1] = v1;
    }
    int cin = cin_base + l;
    int grow0 = mtb * 128 + mr;
    int bb = grow0 >> 11;
    int ktv = (grow0 & 2047) >> 6;
    char* vrow = ws + VT_OFF + (size_t)bb * 2097152 + (size_t)ktv * 65536 +
                 (size_t)cin * 128;
#pragma unroll
    for (int t = 0; t < 8; ++t)  // LINEAR granules
      *(short8*)(vrow + t * 16) = grans[t];
  }
}

// ============================================================
// qk: S(f16, tiled) = Q @ K^T; 128x128 tiles, K=512, BK=64 dbuf
// Q glds-staged (16KB/kt); K-frags DIRECT from global (L2-hot).
// LDS 34.8KB -> 4 blocks/CU. Counted vmcnt keeps prefetch alive.
// ============================================================
__global__ __launch_bounds__(256, 4) void qk_kernel(
    const char* __restrict__ ws, char* __restrict__ Sb, int nb, int b0) {
  __shared__ char smem[34816];  // Q dbuf 2x16KB @0; epilogue [128][272B]
  const int tid = threadIdx.x;
  const int bid = blockIdx.x;
  const int z = bid % nb, tile = bid / nb;  // z==XCD under bid%8 round-robin
  const int mt = tile >> 4, ntq = tile & 15;
  const int b = b0 + z;
  const int l = tid & 63, w = tid >> 6;
  const int g = l >> 4, m16 = l & 15;
  const int fxor = (m16 & 7) << 4;
  const char* Qt = ws + Q_OFF + (size_t)(b * 16 + mt) * 131072;
  const char* Kt = ws + K_OFF + (size_t)(b * 16 + ntq) * 131072;

  auto stage = [&](int buf, int kt) {
#pragma unroll
    for (int j = 0; j < 4; ++j) {
      int idx = j * 256 + tid;
      glds16(Qt + (size_t)kt * 16384 + idx * 16, smem + buf * 16384 + idx * 16);
    }
  };

  const int mr = (w >> 1) * 64, nr = (w & 1) * 64;
  const f32x4 fz = {0.f, 0.f, 0.f, 0.f};
  f32x4 acc[4][4];
#pragma unroll
  for (int i = 0; i < 4; ++i)
#pragma unroll
    for (int j = 0; j < 4; ++j) acc[i][j] = fz;

  stage(0, 0);
  int cur = 0;
#pragma unroll 1
  for (int kt = 0; kt < 8; ++kt) {
    // K-frags for CURRENT kt direct from global — issued first (oldest)
    short8 bf[2][4];
#pragma unroll
    for (int ks = 0; ks < 2; ++ks)
#pragma unroll
      for (int i = 0; i < 4; ++i)
        bf[ks][i] = *(const short8*)(Kt + (size_t)kt * 16384 +
                                     (nr + i * 16 + m16) * 128 + ks * 64 +
                                     g * 16);
    if (kt < 7) {
      stage(cur ^ 1, kt + 1);
      WAITV(12);  // drain only the Q staged one iteration ago
    } else {
      WAITV(8);
    }
    BAR_SYNC();
    const char* Ab = smem + cur * 16384;
#pragma unroll
    for (int ks = 0; ks < 2; ++ks) {
      int off = (16 * g + 64 * ks) ^ fxor;
      short8 af[4];
#pragma unroll
      for (int i = 0; i < 4; ++i)
        af[i] = *(const short8*)(Ab + (mr + i * 16 + m16) * 128 + off);
#pragma unroll
      for (int mi = 0; mi < 4; ++mi)
#pragma unroll
        for (int ni = 0; ni < 4; ++ni)
          acc[mi][ni] = mfma16(af[mi], bf[ks][ni], acc[mi][ni]);
    }
    BAR_LGKM();
    cur ^= 1;
  }

  // ---- epilogue: f16 repack [128][272B] in LDS, then packed tiled stores --
#pragma unroll
  for (int mi = 0; mi < 4; ++mi)
#pragma unroll
    for (int ni = 0; ni < 4; ++ni)
#pragma unroll
      for (int j = 0; j < 4; ++j) {
        int r = mr + mi * 16 + g * 4 + j, c = nr + ni * 16 + m16;
        *(unsigned short*)(smem + r * 272 + 2 * c) =
            __builtin_bit_cast(unsigned short, (_Float16)acc[mi][ni][j]);
      }
  BAR_LGKM();
  char* Sbt = Sb + (size_t)z * 8388608;
#pragma unroll
  for (int it = 0; it < 8; ++it) {
    int idx = it * 256 + tid;
    int r = idx >> 4, gi = idx & 15;
    int rg = mt * 2 + (r >> 6), ck = ntq * 2 + (gi >> 3);
    *(short8*)(Sbt + ((size_t)(rg * 32 + ck) * 64 + (r & 63)) * 128 +
               (gi & 7) * 16) = *(const short8*)(smem + r * 272 + gi * 16);
  }
}

// ============================================================
// stats: row softmax on f16 S tiles; writes bf16 P in place (swizzled
// granules for pv's LDS frag reads). One wave per row.
// ============================================================
__global__ __launch_bounds__(256, 8) void stats_kernel(char* __restrict__ Sb) {
  const int w = threadIdx.x >> 6, l = threadIdx.x & 63;
  const size_t row = (size_t)blockIdx.x * 4 + w;
  const int z = (int)(row >> 11), rloc = (int)(row & 2047);
  const int rg = rloc >> 6, r64 = rloc & 63;
  const int f = (rloc & 7) << 4;
  char* base = Sb + (size_t)z * 8388608 + (size_t)rg * 262144 +
               (size_t)r64 * 128;
  float sv[32];
#pragma unroll
  for (int i = 0; i < 4; ++i) {
    int idx = i * 64 + l;
    int ck = idx >> 3, gi = idx & 7;
    h8 hv = *(const h8*)(base + (size_t)ck * 8192 + gi * 16);
#pragma unroll
    for (int j = 0; j < 8; ++j) sv[i * 8 + j] = (float)hv[j];
  }
  float m = sv[0];
#pragma unroll
  for (int i = 1; i < 32; ++i) m = fmaxf(m, sv[i]);
  m = fmaxf(m, __shfl_xor(m, 1));
  m = fmaxf(m, __shfl_xor(m, 2));
  m = fmaxf(m, __shfl_xor(m, 4));
  m = fmaxf(m, __shfl_xor(m, 8));
  m = fmaxf(m, __shfl_xor(m, 16));
  m = fmaxf(m, __shfl_xor(m, 32));
  float sum = 0.f;
#pragma unroll
  for (int i = 0; i < 32; ++i) {
    float p = exp2f(sv[i] - m);
    sv[i] = p;
    sum += p;
  }
  sum += __shfl_xor(sum, 1);
  sum += __shfl_xor(sum, 2);
  sum += __shfl_xor(sum, 4);
  sum += __shfl_xor(sum, 8);
  sum += __shfl_xor(sum, 16);
  sum += __shfl_xor(sum, 32);
  const float rs = 1.0f / sum;
#pragma unroll
  for (int i = 0; i < 4; ++i) {
    int idx = i * 64 + l;
    int ck = idx >> 3, gi = idx & 7;
    short8 pk;
#pragma unroll
    for (int j = 0; j < 8; ++j) pk[j] = (short)f2bf(sv[i * 8 + j] * rs);
    *(short8*)(base + (size_t)ck * 8192 + ((gi * 16) ^ f)) = pk;
  }
}

// ============================================================
// pv: O = P @ V, fused fc2/bias/leakyrelu/residual epilogue
// block = 64 q-rows x 512 v-cols; 8 waves (wave w: cols w*64..+64)
// K=2048 -> 32 kt of BK=64. P glds-staged dbuf (8KB/kt, reused 8x);
// V-frags DIRECT from global (L2-hot, batch->XCD affinity via z=bid%8).
// LDS 64KB -> 2 blocks/CU (4 waves/SIMD).
// ============================================================
__global__ __launch_bounds__(512, 4) void pv_kernel(
    const char* __restrict__ ws, const char* __restrict__ Sb,
    const float* __restrict__ feat, const float* __restrict__ b2,
    float* __restrict__ out, int nb, int b0) {
  __shared__ char smem[65536];  // P dbuf 2x4KB... [0,16KB); epi O [64][1024B]
  const int tid = threadIdx.x;
  const int bid = blockIdx.x;
  const int z = bid % nb, mt64 = bid / nb;  // z==XCD under bid%8 round-robin
  const int b = b0 + z;
  const int l = tid & 63, w = tid >> 6;
  const int g = l >> 4, m16 = l & 15;
  const int fxor = (m16 & 7) << 4;
  const char* Pr = Sb + (size_t)z * 8388608 + (size_t)mt64 * 262144;
  const char* Vt = ws + VT_OFF + (size_t)b * 2097152;

  auto stage = [&](int buf, int kt) {  // P: 8KB, 1 glds/thread
    glds16(Pr + (size_t)kt * 8192 + tid * 16, smem + buf * 8192 + tid * 16);
  };

  const f32x4 fz = {0.f, 0.f, 0.f, 0.f};
  f32x4 acc[4][4];
#pragma unroll
  for (int i = 0; i < 4; ++i)
#pragma unroll
    for (int j = 0; j < 4; ++j) acc[i][j] = fz;

  stage(0, 0);
  int cur = 0;
#pragma unroll 1
  for (int kt = 0; kt < 32; ++kt) {
    // V-frags for CURRENT kt direct from global — issued first (oldest)
    const char* Vk = Vt + (size_t)kt * 65536;
    short8 vf[2][4];
#pragma unroll
    for (int ks = 0; ks < 2; ++ks)
#pragma unroll
      for (int i = 0; i < 4; ++i)
        vf[ks][i] = *(const short8*)(Vk + (w * 64 + i * 16 + m16) * 128 +
                                     ks * 64 + g * 16);
    if (kt < 31) {
      stage(cur ^ 1, kt + 1);
      WAITV(9);  // drain only the P staged one iteration ago
    } else {
      WAITV(8);
    }
    BAR_SYNC();
    const char* Ab = smem + cur * 8192;
#pragma unroll
    for (int ks = 0; ks < 2; ++ks) {
      int off = (16 * g + 64 * ks) ^ fxor;
      short8 af[4];
#pragma unroll
      for (int i = 0; i < 4; ++i)
        af[i] = *(const short8*)(Ab + (i * 16 + m16) * 128 + off);
#pragma unroll
      for (int mi = 0; mi < 4; ++mi)
#pragma unroll
        for (int ni = 0; ni < 4; ++ni)
          acc[mi][ni] = mfma16(af[mi], vf[ks][ni], acc[mi][ni]);
    }
    BAR_LGKM();
    cur ^= 1;
  }

  // ---- repack O (bf16, row-swizzled) into LDS [64][1024B] @0 ----
  char* Ob = smem;
#pragma unroll
  for (int mi = 0; mi < 4; ++mi)
#pragma unroll
    for (int ni = 0; ni < 4; ++ni)
#pragma unroll
      for (int j = 0; j < 4; ++j) {
        int r = mi * 16 + g * 4 + j;
        int c = w * 64 + ni * 16 + m16;
        *(unsigned short*)(Ob + r * 1024 + ((2 * c) ^ ((r & 7) << 4))) =
            f2bf(acc[mi][ni][j]);
      }
  BAR_LGKM();

  // ---- fc2: Y[64 x 256] = O @ W2 (+bias, lrelu, +residual) ----
  const char* W2g = ws + W2T_OFF;
  f32x4 y[4][2];
#pragma unroll
  for (int i = 0; i < 4; ++i) {
    y[i][0] = fz;
    y[i][1] = fz;
  }
#pragma unroll 1
  for (int ks = 0; ks < 16; ++ks) {
    int off = (ks * 64 + 16 * g);
    short8 aa[4], wb[2];
#pragma unroll
    for (int mi2 = 0; mi2 < 4; ++mi2) {
      int r = mi2 * 16 + m16;
      aa[mi2] = *(const short8*)(Ob + r * 1024 + (off ^ fxor));
    }
#pragma unroll
    for (int ni2 = 0; ni2 < 2; ++ni2) {
      int d = w * 32 + ni2 * 16 + m16;
      wb[ni2] = *(const short8*)(W2g + (size_t)d * 1024 + ks * 64 + g * 16);
    }
#pragma unroll
    for (int mi2 = 0; mi2 < 4; ++mi2)
#pragma unroll
      for (int ni2 = 0; ni2 < 2; ++ni2)
        y[mi2][ni2] = mfma16(aa[mi2], wb[ni2], y[mi2][ni2]);
  }
#pragma unroll
  for (int mi2 = 0; mi2 < 4; ++mi2)
#pragma unroll
    for (int ni2 = 0; ni2 < 2; ++ni2) {
      int d = w * 32 + ni2 * 16 + m16;
      float bias = b2[d];
#pragma unroll
      for (int j = 0; j < 4; ++j) {
        size_t gr = (size_t)b * 2048 + mt64 * 64 + mi2 * 16 + g * 4 + j;
        float v = y[mi2][ni2][j] + bias;
        v = v > 0.f ? v : 0.2f * v;
        out[gr * 256 + d] = v + feat[gr * 256 + d];
      }
    }
}

// ============================================================
extern "C" void kernel_launch(void* const* d_in, const int* in_sizes, int n_in,
                              void* d_out, int out_size, void* d_ws, size_t ws_size,
                              hipStream_t stream) {
  const float* feat = (const float*)d_in[0];
  const float* Wq = (const float*)d_in[1];
  const float* Wk = (const float*)d_in[2];
  const float* Wv = (const float*)d_in[3];
  const float* W2 = (const float*)d_in[4];
  const float* b2 = (const float*)d_in[5];
  float* out = (float*)d_out;
  char* ws = (char*)d_ws;
  (void)in_sizes; (void)n_in; (void)out_size;

  prep_kernel<<<4096, 256, 0, stream>>>(feat, Wq, Wk, Wv, W2, ws);
  proj_kernel<<<1536, 256, 0, stream>>>(ws);

  const size_t per_batch = 8388608ul;  // f16/bf16 S: 2048 rows * 4096 B
  int nb = 8;
  while (nb > 1 && S_OFF + (size_t)nb * per_batch > ws_size) nb >>= 1;
  char* Sb = ws + S_OFF;
  for (int b0 = 0; b0 < 8; b0 += nb) {
    qk_kernel<<<256 * nb, 256, 0, stream>>>(ws, Sb, nb, b0);
    stats_kernel<<<512 * nb, 256, 0, stream>>>(Sb);
    pv_kernel<<<32 * nb, 512, 0, stream>>>(ws, Sb, feat, b2, out, nb, b0);
  }
}

// Round 9
// 214.486 us; speedup vs baseline: 1.0206x; 1.0206x over previous
//
#include <hip/hip_runtime.h>
#include <cstdint>

// ---------------- problem constants ----------------
// features [8,2048,256] f32; Wq/Wk/Wv [256,512]; W2 [512,256]; b2 [256]
// out [8,2048,256] f32
#define NBATCH 8
#define NSEQ   2048
#define NROWS  16384

typedef __attribute__((ext_vector_type(4))) float  f32x4;
typedef __attribute__((ext_vector_type(8))) short  short8;
typedef __attribute__((ext_vector_type(8))) __bf16 bf16x8;
typedef __attribute__((ext_vector_type(8))) _Float16 h8;

// ---------------- workspace layout (bytes) ----------------
// Xb/Wall: row-granule-swizzled bf16 (16B granule index ^= row&7 within row)
// Q  : TILED [t 128][ck 8][r 128][128B], granules stored[p]=true[p^(r&7)]
//      (Q is glds-staged into LDS -> needs the bank swizzle)
// K  : TILED [t 128][ck 8][r 128][128B], granules LINEAR (read direct from L2)
// Vt : TILED [b 8][ktv 32][c 512][128B], granules LINEAR (read direct from L2)
// W2t: LINEAR [256 d][512 c] bf16 (read direct from global in fc2)
// S/P: TILED  [z][rg 32][ck 32][r64 64][128B]; f16 S (linear granules) is
//      overwritten in place by bf16 P (granules stored[p]=true[p^(r&7)],
//      since P IS glds-staged by pv)
#define XB_OFF   0ul          // 8388608
#define WALL_OFF 8388608ul    // 786432 (Wq^T*scale | Wk^T | Wv^T)
#define Q_OFF    9175040ul    // 16777216 (pre-scaled by log2e/sqrt(512))
#define K_OFF    25952256ul   // 16777216
#define VT_OFF   42729472ul   // 16777216
#define W2T_OFF  59506688ul   // 262144
#define S_OFF    59768832ul   // nb * 8388608

#define SCALE_Q 0.063758746f  // (1/sqrt(512)) * log2(e)

__device__ __forceinline__ unsigned short f2bf(float f) {
  unsigned u = __builtin_bit_cast(unsigned, f);
  return (unsigned short)((u + 0x7fffu + ((u >> 16) & 1u)) >> 16);  // RNE
}

__device__ __forceinline__ f32x4 mfma16(short8 a, short8 b, f32x4 c) {
  return __builtin_amdgcn_mfma_f32_16x16x32_bf16(
      __builtin_bit_cast(bf16x8, a), __builtin_bit_cast(bf16x8, b), c, 0, 0, 0);
}

__device__ __forceinline__ void glds16(const void* g, void* l) {
  __builtin_amdgcn_global_load_lds(
      (const __attribute__((address_space(1))) void*)g,
      (__attribute__((address_space(3))) void*)l, 16, 0, 0);
}

#define BAR_SYNC()                     \
  {                                    \
    __builtin_amdgcn_sched_barrier(0); \
    __builtin_amdgcn_s_barrier();      \
    __builtin_amdgcn_sched_barrier(0); \
  }
#define BAR_LGKM()                                           \
  {                                                          \
    asm volatile("s_waitcnt lgkmcnt(0)" ::: "memory");       \
    __builtin_amdgcn_sched_barrier(0);                       \
    __builtin_amdgcn_s_barrier();                            \
    __builtin_amdgcn_sched_barrier(0);                       \
  }
#define WAITV(N)                                                  \
  {                                                               \
    __builtin_amdgcn_sched_barrier(0);                            \
    asm volatile("s_waitcnt vmcnt(" #N ")" ::: "memory");         \
    __builtin_amdgcn_sched_barrier(0);                            \
  }

// ============================================================
// prep: bf16 conversions + transposes + swizzled layouts
// ============================================================
__global__ __launch_bounds__(256, 4) void prep_kernel(
    const float* __restrict__ feat, const float* __restrict__ Wq,
    const float* __restrict__ Wk, const float* __restrict__ Wv,
    const float* __restrict__ W2, char* __restrict__ ws) {
  int tid = blockIdx.x * 256 + threadIdx.x;
  if (tid < 524288) {  // Xb: 8-elem chunks
    int r = tid >> 5, co = (tid & 31) * 8;
    const float* src = feat + (size_t)r * 256 + co;
    short8 v;
#pragma unroll
    for (int i = 0; i < 8; ++i) v[i] = (short)f2bf(src[i]);
    unsigned short* Xb = (unsigned short*)(ws + XB_OFF);
    *(short8*)(Xb + (size_t)r * 256 + (co ^ ((r & 7) << 3))) = v;
  } else if (tid < 917504) {  // Wall[m][d] = W*[d][m] (scale folded into Wq)
    int t2 = tid - 524288;
    int m = t2 >> 8, d = t2 & 255;
    int wsel = m >> 9, mm = m & 511;
    const float* W = (wsel == 0) ? Wq : ((wsel == 1) ? Wk : Wv);
    float v = W[(size_t)d * 512 + mm];
    if (wsel == 0) v *= SCALE_Q;
    unsigned short* Wall = (unsigned short*)(ws + WALL_OFF);
    Wall[(size_t)m * 256 + (d ^ ((m & 7) << 3))] = f2bf(v);
  } else {  // W2t[d][c] = W2[c][d]  (LINEAR)
    int t3 = tid - 917504;
    int d = t3 >> 9, c = t3 & 511;
    unsigned short* W2t = (unsigned short*)(ws + W2T_OFF);
    W2t[(size_t)d * 512 + c] = f2bf(W2[(size_t)c * 256 + d]);
  }
}

// ============================================================
// proj: [16384,256] @ [256, 512*3] -> Q (swz), K (linear), Vt (linear)
// 1536 blocks (XCD-chunked swizzle), 4 waves, 128x128 tile, BK=64 dbuf
// ============================================================
__global__ __launch_bounds__(256, 2) void proj_kernel(char* __restrict__ ws) {
  __shared__ char smem[65536];  // A dbuf 2x16KB @0, B dbuf 2x16KB @32768
  const int tid = threadIdx.x;
  const int l = tid & 63, w = tid >> 6;
  const int g = l >> 4, m16 = l & 15;
  const int orig = blockIdx.x;
  const int wgid = (orig & 7) * 192 + (orig >> 3);  // 1536%8==0, bijective
  const int nt = wgid % 12, mtb = wgid / 12;
  const char* XbT = ws + XB_OFF + (size_t)mtb * 65536;     // [128 r][512B]
  const char* WallT = ws + WALL_OFF + (size_t)nt * 65536;  // [128 r][512B]

  auto stage = [&](int buf, int kt) {
#pragma unroll
    for (int j = 0; j < 4; ++j) {
      int idx = j * 256 + tid;  // 0..1023: r=idx>>3, p=idx&7
      int r = idx >> 3, p = idx & 7;
      glds16(XbT + r * 512 + kt * 128 + p * 16, smem + buf * 16384 + idx * 16);
      glds16(WallT + r * 512 + kt * 128 + p * 16,
             smem + 32768 + buf * 16384 + idx * 16);
    }
  };

  const int mr = (w >> 1) * 64, nr = (w & 1) * 64;
  const int fxor = (m16 & 7) << 4;
  const f32x4 fz = {0.f, 0.f, 0.f, 0.f};
  f32x4 acc[4][4];
#pragma unroll
  for (int i = 0; i < 4; ++i)
#pragma unroll
    for (int j = 0; j < 4; ++j) acc[i][j] = fz;

  stage(0, 0);
  int cur = 0;
#pragma unroll 1
  for (int kt = 0; kt < 4; ++kt) {
    if (kt < 3) {
      stage(cur ^ 1, kt + 1);
      WAITV(8);
    } else {
      WAITV(0);
    }
    BAR_SYNC();
    const char* Ab = smem + cur * 16384;
    const char* Bb = smem + 32768 + cur * 16384;
#pragma unroll
    for (int ks = 0; ks < 2; ++ks) {
      int off = (16 * g + 64 * ks) ^ fxor;
      short8 af[4], bf[4];
#pragma unroll
      for (int i = 0; i < 4; ++i)
        af[i] = *(const short8*)(Ab + (mr + i * 16 + m16) * 128 + off);
#pragma unroll
      for (int i = 0; i < 4; ++i)
        bf[i] = *(const short8*)(Bb + (nr + i * 16 + m16) * 128 + off);
#pragma unroll
      for (int mi = 0; mi < 4; ++mi)
#pragma unroll
        for (int ni = 0; ni < 4; ++ni)
          acc[mi][ni] = mfma16(af[mi], bf[ni], acc[mi][ni]);
    }
    BAR_LGKM();
    cur ^= 1;
  }

  // ---- epilogue ----
  const int colg = nt * 128 + nr;
  const int tcat = colg >> 9;       // 0=Q 1=K 2=V
  const int cin_base = colg & 511;  // col within tensor
  char* wbuf = smem + w * 2048;     // per-wave [16][128B]
  if (tcat < 2) {
    char* dst = ws + (tcat == 0 ? Q_OFF : K_OFF) +
                ((size_t)(mtb * 8 + (cin_base >> 6))) * 16384;
#pragma unroll
    for (int mi = 0; mi < 4; ++mi) {
#pragma unroll
      for (int ni = 0; ni < 4; ++ni)
#pragma unroll
        for (int j = 0; j < 4; ++j) {
          int r = g * 4 + j, c = ni * 16 + m16;
          *(unsigned short*)(wbuf + r * 128 + ((2 * c) ^ ((r & 7) << 4))) =
              f2bf(acc[mi][ni][j]);
        }
      asm volatile("s_waitcnt lgkmcnt(0)" ::: "memory");
      __builtin_amdgcn_sched_barrier(0);
#pragma unroll
      for (int s = 0; s < 2; ++s) {
        int cid = l + 64 * s;
        int r2 = cid >> 3, gi = cid & 7;
        // Q keeps LDS-swizzled granules; K stored LINEAR (direct-L2 reads)
        int slot = (tcat == 0) ? gi : (gi ^ (r2 & 7));
        short8 v = *(const short8*)(wbuf + r2 * 128 + slot * 16);
        int rt = mr + mi * 16 + r2;  // row in tile
        *(short8*)(dst + (size_t)rt * 128 + gi * 16) = v;
      }
    }
  } else {
    // V: gather column l per mi into registers, write each 128B row ONCE
    short8 grans[8];
#pragma unroll
    for (int mi = 0; mi < 4; ++mi) {
#pragma unroll
      for (int ni = 0; ni < 4; ++ni)
#pragma unroll
        for (int j = 0; j < 4; ++j) {
          int r = g * 4 + j, c = ni * 16 + m16;
          *(unsigned short*)(wbuf + r * 128 + ((2 * c) ^ ((r & 7) << 4))) =
              f2bf(acc[mi][ni][j]);
        }
      asm volatile("s_waitcnt lgkmcnt(0)" ::: "memory");
      __builtin_amdgcn_sched_barrier(0);
      unsigned short vals[16];
#pragma unroll
      for (int r2 = 0; r2 < 16; ++r2)
        vals[r2] = *(const unsigned short*)(wbuf + r2 * 128 +
                                            ((2 * l) ^ ((r2 & 7) << 4)));
      short8 v0, v1;
#pragma unroll
      for (int i2 = 0; i2 < 8; ++i2) {
        v0[i2] = (short)vals[i2];
        v1[i2] = (short)vals[8 + i2];
      }
      grans[2 * mi] = v0;
      grans[2 * mi + 1] = v1;
    }
    int cin = cin_base + l;
    int grow0 = mtb * 128 + mr;
    int bb = grow0 >> 11;
    int ktv = (grow0 & 2047) >> 6;
    char* vrow = ws + VT_OFF + (size_t)bb * 2097152 + (size_t)ktv * 65536 +
                 (size_t)cin * 128;
#pragma unroll
    for (int t = 0; t < 8; ++t)  // LINEAR granules
      *(short8*)(vrow + t * 16) = grans[t];
  }
}

// ============================================================
// qk: S(f16, tiled) = Q @ K^T; 128x128 tiles, K=512, BK=64 dbuf
// Q glds-staged (4 glds/thread); K-frags DIRECT from L2 with 1-kt
// REGISTER PREFETCH (bfA/bfB, unroll-by-2). WAITV(12) = bf(8)+Q(4).
// ============================================================
__global__ __launch_bounds__(256, 2) void qk_kernel(
    const char* __restrict__ ws, char* __restrict__ Sb, int nb, int b0) {
  __shared__ char smem[34816];  // Q dbuf 2x16KB @0; epilogue [128][272B]
  const int tid = threadIdx.x;
  const int bid = blockIdx.x;
  const int z = bid % nb, tile = bid / nb;  // z==XCD under bid%8 round-robin
  const int mt = tile >> 4, ntq = tile & 15;
  const int b = b0 + z;
  const int l = tid & 63, w = tid >> 6;
  const int g = l >> 4, m16 = l & 15;
  const int fxor = (m16 & 7) << 4;
  const char* Qt = ws + Q_OFF + (size_t)(b * 16 + mt) * 131072;
  const char* Kt = ws + K_OFF + (size_t)(b * 16 + ntq) * 131072;

  const int mr = (w >> 1) * 64, nr = (w & 1) * 64;
  const f32x4 fz = {0.f, 0.f, 0.f, 0.f};
  f32x4 acc[4][4];
#pragma unroll
  for (int i = 0; i < 4; ++i)
#pragma unroll
    for (int j = 0; j < 4; ++j) acc[i][j] = fz;

  auto loadbf = [&](short8(&bf)[8], int kt) {
    const char* Kk = Kt + (size_t)kt * 16384 + g * 16;
#pragma unroll
    for (int ks = 0; ks < 2; ++ks)
#pragma unroll
      for (int i = 0; i < 4; ++i)
        bf[ks * 4 + i] =
            *(const short8*)(Kk + (nr + i * 16 + m16) * 128 + ks * 64);
  };
  auto stageQ = [&](int buf, int kt) {
#pragma unroll
    for (int j = 0; j < 4; ++j) {
      int idx = j * 256 + tid;
      glds16(Qt + (size_t)kt * 16384 + idx * 16, smem + buf * 16384 + idx * 16);
    }
  };
  auto compute = [&](int buf, short8(&bf)[8]) {
    const char* Ab = smem + buf * 16384;
#pragma unroll
    for (int ks = 0; ks < 2; ++ks) {
      int off = (16 * g + 64 * ks) ^ fxor;
      short8 af[4];
#pragma unroll
      for (int i = 0; i < 4; ++i)
        af[i] = *(const short8*)(Ab + (mr + i * 16 + m16) * 128 + off);
#pragma unroll
      for (int mi = 0; mi < 4; ++mi)
#pragma unroll
        for (int ni = 0; ni < 4; ++ni)
          acc[mi][ni] = mfma16(af[mi], bf[ks * 4 + ni], acc[mi][ni]);
    }
  };

  short8 bfA[8], bfB[8];
  loadbf(bfA, 0);
  stageQ(0, 0);
#pragma unroll 1
  for (int kt2 = 0; kt2 < 4; ++kt2) {
    const int kt = kt2 * 2;
    loadbf(bfB, kt + 1);
    stageQ(1, kt + 1);
    WAITV(12);
    BAR_SYNC();
    compute(0, bfA);
    BAR_LGKM();
    if (kt + 2 < 8) {
      loadbf(bfA, kt + 2);
      stageQ(0, kt + 2);
      WAITV(12);
    } else {
      WAITV(0);
    }
    BAR_SYNC();
    compute(1, bfB);
    BAR_LGKM();
  }

  // ---- epilogue: f16 repack [128][272B] in LDS, then packed tiled stores --
#pragma unroll
  for (int mi = 0; mi < 4; ++mi)
#pragma unroll
    for (int ni = 0; ni < 4; ++ni)
#pragma unroll
      for (int j = 0; j < 4; ++j) {
        int r = mr + mi * 16 + g * 4 + j, c = nr + ni * 16 + m16;
        *(unsigned short*)(smem + r * 272 + 2 * c) =
            __builtin_bit_cast(unsigned short, (_Float16)acc[mi][ni][j]);
      }
  BAR_LGKM();
  char* Sbt = Sb + (size_t)z * 8388608;
#pragma unroll
  for (int it = 0; it < 8; ++it) {
    int idx = it * 256 + tid;
    int r = idx >> 4, gi = idx & 15;
    int rg = mt * 2 + (r >> 6), ck = ntq * 2 + (gi >> 3);
    *(short8*)(Sbt + ((size_t)(rg * 32 + ck) * 64 + (r & 63)) * 128 +
               (gi & 7) * 16) = *(const short8*)(smem + r * 272 + gi * 16);
  }
}

// ============================================================
// stats: row softmax on f16 S tiles; writes bf16 P in place (swizzled
// granules for pv's LDS frag reads). One wave per row.
// ============================================================
__global__ __launch_bounds__(256, 8) void stats_kernel(char* __restrict__ Sb) {
  const int w = threadIdx.x >> 6, l = threadIdx.x & 63;
  const size_t row = (size_t)blockIdx.x * 4 + w;
  const int z = (int)(row >> 11), rloc = (int)(row & 2047);
  const int rg = rloc >> 6, r64 = rloc & 63;
  const int f = (rloc & 7) << 4;
  char* base = Sb + (size_t)z * 8388608 + (size_t)rg * 262144 +
               (size_t)r64 * 128;
  float sv[32];
#pragma unroll
  for (int i = 0; i < 4; ++i) {
    int idx = i * 64 + l;
    int ck = idx >> 3, gi = idx & 7;
    h8 hv = *(const h8*)(base + (size_t)ck * 8192 + gi * 16);
#pragma unroll
    for (int j = 0; j < 8; ++j) sv[i * 8 + j] = (float)hv[j];
  }
  float m = sv[0];
#pragma unroll
  for (int i = 1; i < 32; ++i) m = fmaxf(m, sv[i]);
  m = fmaxf(m, __shfl_xor(m, 1));
  m = fmaxf(m, __shfl_xor(m, 2));
  m = fmaxf(m, __shfl_xor(m, 4));
  m = fmaxf(m, __shfl_xor(m, 8));
  m = fmaxf(m, __shfl_xor(m, 16));
  m = fmaxf(m, __shfl_xor(m, 32));
  float sum = 0.f;
#pragma unroll
  for (int i = 0; i < 32; ++i) {
    float p = exp2f(sv[i] - m);
    sv[i] = p;
    sum += p;
  }
  sum += __shfl_xor(sum, 1);
  sum += __shfl_xor(sum, 2);
  sum += __shfl_xor(sum, 4);
  sum += __shfl_xor(sum, 8);
  sum += __shfl_xor(sum, 16);
  sum += __shfl_xor(sum, 32);
  const float rs = 1.0f / sum;
#pragma unroll
  for (int i = 0; i < 4; ++i) {
    int idx = i * 64 + l;
    int ck = idx >> 3, gi = idx & 7;
    short8 pk;
#pragma unroll
    for (int j = 0; j < 8; ++j) pk[j] = (short)f2bf(sv[i * 8 + j] * rs);
    *(short8*)(base + (size_t)ck * 8192 + ((gi * 16) ^ f)) = pk;
  }
}

// ============================================================
// pv: O = P @ V, fused fc2/bias/leakyrelu/residual epilogue
// block = 64 q-rows x 512 v-cols; 8 waves (wave w: cols w*64..+64)
// K=2048 -> 32 kt of BK=64. P glds-staged dbuf (1 glds/thread);
// V-frags DIRECT from L2 with 1-kt REGISTER PREFETCH (vfA/vfB,
// unroll-by-2). WAITV(9) = vf(8)+P(1). LDS 64KB.
// ============================================================
__global__ __launch_bounds__(512, 2) void pv_kernel(
    const char* __restrict__ ws, const char* __restrict__ Sb,
    const float* __restrict__ feat, const float* __restrict__ b2,
    float* __restrict__ out, int nb, int b0) {
  __shared__ char smem[65536];  // P dbuf 2x8KB @0..16K; epi O [64][1024B] @0
  const int tid = threadIdx.x;
  const int bid = blockIdx.x;
  const int z = bid % nb, mt64 = bid / nb;  // z==XCD under bid%8 round-robin
  const int b = b0 + z;
  const int l = tid & 63, w = tid >> 6;
  const int g = l >> 4, m16 = l & 15;
  const int fxor = (m16 & 7) << 4;
  const char* Pr = Sb + (size_t)z * 8388608 + (size_t)mt64 * 262144;
  const char* Vt = ws + VT_OFF + (size_t)b * 2097152;

  const f32x4 fz = {0.f, 0.f, 0.f, 0.f};
  f32x4 acc[4][4];
#pragma unroll
  for (int i = 0; i < 4; ++i)
#pragma unroll
    for (int j = 0; j < 4; ++j) acc[i][j] = fz;

  auto loadvf = [&](short8(&vf)[8], int kt) {
    const char* Vk = Vt + (size_t)kt * 65536 + g * 16;
#pragma unroll
    for (int ks = 0; ks < 2; ++ks)
#pragma unroll
      for (int i = 0; i < 4; ++i)
        vf[ks * 4 + i] =
            *(const short8*)(Vk + (w * 64 + i * 16 + m16) * 128 + ks * 64);
  };
  auto stageP = [&](int buf, int kt) {
    glds16(Pr + (size_t)kt * 8192 + tid * 16, smem + buf * 8192 + tid * 16);
  };
  auto compute = [&](int buf, short8(&vf)[8]) {
    const char* Ab = smem + buf * 8192;
#pragma unroll
    for (int ks = 0; ks < 2; ++ks) {
      int off = (16 * g + 64 * ks) ^ fxor;
      short8 af[4];
#pragma unroll
      for (int i = 0; i < 4; ++i)
        af[i] = *(const short8*)(Ab + (i * 16 + m16) * 128 + off);
#pragma unroll
      for (int mi = 0; mi < 4; ++mi)
#pragma unroll
        for (int ni = 0; ni < 4; ++ni)
          acc[mi][ni] = mfma16(af[mi], vf[ks * 4 + ni], acc[mi][ni]);
    }
  };

  short8 vfA[8], vfB[8];
  loadvf(vfA, 0);
  stageP(0, 0);
#pragma unroll 1
  for (int kt2 = 0; kt2 < 16; ++kt2) {
    const int kt = kt2 * 2;
    loadvf(vfB, kt + 1);
    stageP(1, kt + 1);
    WAITV(9);
    BAR_SYNC();
    compute(0, vfA);
    BAR_LGKM();
    if (kt + 2 < 32) {
      loadvf(vfA, kt + 2);
      stageP(0, kt + 2);
      WAITV(9);
    } else {
      WAITV(0);
    }
    BAR_SYNC();
    compute(1, vfB);
    BAR_LGKM();
  }

  // ---- repack O (bf16, row-swizzled) into LDS [64][1024B] @0 ----
  char* Ob = smem;
#pragma unroll
  for (int mi = 0; mi < 4; ++mi)
#pragma unroll
    for (int ni = 0; ni < 4; ++ni)
#pragma unroll
      for (int j = 0; j < 4; ++j) {
        int r = mi * 16 + g * 4 + j;
        int c = w * 64 + ni * 16 + m16;
        *(unsigned short*)(Ob + r * 1024 + ((2 * c) ^ ((r & 7) << 4))) =
            f2bf(acc[mi][ni][j]);
      }
  BAR_LGKM();

  // ---- fc2: Y[64 x 256] = O @ W2 (+bias, lrelu, +residual) ----
  const char* W2g = ws + W2T_OFF;
  f32x4 y[4][2];
#pragma unroll
  for (int i = 0; i < 4; ++i) {
    y[i][0] = fz;
    y[i][1] = fz;
  }
#pragma unroll 1
  for (int ks = 0; ks < 16; ++ks) {
    int off = (ks * 64 + 16 * g);
    short8 aa[4], wb[2];
#pragma unroll
    for (int mi2 = 0; mi2 < 4; ++mi2) {
      int r = mi2 * 16 + m16;
      aa[mi2] = *(const short8*)(Ob + r * 1024 + (off ^ fxor));
    }
#pragma unroll
    for (int ni2 = 0; ni2 < 2; ++ni2) {
      int d = w * 32 + ni2 * 16 + m16;
      wb[ni2] = *(const short8*)(W2g + (size_t)d * 1024 + ks * 64 + g * 16);
    }
#pragma unroll
    for (int mi2 = 0; mi2 < 4; ++mi2)
#pragma unroll
      for (int ni2 = 0; ni2 < 2; ++ni2)
        y[mi2][ni2] = mfma16(aa[mi2], wb[ni2], y[mi2][ni2]);
  }
#pragma unroll
  for (int mi2 = 0; mi2 < 4; ++mi2)
#pragma unroll
    for (int ni2 = 0; ni2 < 2; ++ni2) {
      int d = w * 32 + ni2 * 16 + m16;
      float bias = b2[d];
#pragma unroll
      for (int j = 0; j < 4; ++j) {
        size_t gr = (size_t)b * 2048 + mt64 * 64 + mi2 * 16 + g * 4 + j;
        float v = y[mi2][ni2][j] + bias;
        v = v > 0.f ? v : 0.2f * v;
        out[gr * 256 + d] = v + feat[gr * 256 + d];
      }
    }
}

// ============================================================
extern "C" void kernel_launch(void* const* d_in, const int* in_sizes, int n_in,
                              void* d_out, int out_size, void* d_ws, size_t ws_size,
                              hipStream_t stream) {
  const float* feat = (const float*)d_in[0];
  const float* Wq = (const float*)d_in[1];
  const float* Wk = (const float*)d_in[2];
  const float* Wv = (const float*)d_in[3];
  const float* W2 = (const float*)d_in[4];
  const float* b2 = (const float*)d_in[5];
  float* out = (float*)d_out;
  char* ws = (char*)d_ws;
  (void)in_sizes; (void)n_in; (void)out_size;

  prep_kernel<<<4096, 256, 0, stream>>>(feat, Wq, Wk, Wv, W2, ws);
  proj_kernel<<<1536, 256, 0, stream>>>(ws);

  const size_t per_batch = 8388608ul;  // f16/bf16 S: 2048 rows * 4096 B
  int nb = 8;
  while (nb > 1 && S_OFF + (size_t)nb * per_batch > ws_size) nb >>= 1;
  char* Sb = ws + S_OFF;
  for (int b0 = 0; b0 < 8; b0 += nb) {
    qk_kernel<<<256 * nb, 256, 0, stream>>>(ws, Sb, nb, b0);
    stats_kernel<<<512 * nb, 256, 0, stream>>>(Sb);
    pv_kernel<<<32 * nb, 512, 0, stream>>>(ws, Sb, feat, b2, out, nb, b0);
  }
}

// Round 10
// 204.929 us; speedup vs baseline: 1.0682x; 1.0466x over previous
//
#include <hip/hip_runtime.h>
#include <cstdint>

// ---------------- problem constants ----------------
// features [8,2048,256] f32; Wq/Wk/Wv [256,512]; W2 [512,256]; b2 [256]
// out [8,2048,256] f32
#define NBATCH 8
#define NSEQ   2048
#define NROWS  16384

typedef __attribute__((ext_vector_type(4))) float  f32x4;
typedef __attribute__((ext_vector_type(8))) short  short8;
typedef __attribute__((ext_vector_type(8))) __bf16 bf16x8;
typedef __attribute__((ext_vector_type(8))) _Float16 h8;

// ---------------- workspace layout (bytes) ----------------
// Xb/Wall: row-granule-swizzled bf16 (16B granule index ^= row&7 within row)
// Q/K : TILED [t 128][ck 8][r 128][128B], granules stored[p]=true[p^(r&7)]
//       (glds-staged into LDS -> bank swizzle pre-baked)
// Vt  : TILED [b 8][ktv 32][c 512][128B], granules stored[p]=true[p^(c&7)]
// W2t : LINEAR [256 d][512 c] bf16 (read direct from global in fc2)
// S/P : TILED [z][rg 32][ck 32][r64 64][128B]; f16 S (linear granules) is
//       overwritten in place by bf16 P, LINEAR granules (pv reads P direct
//       to registers via L1-broadcast -> no LDS swizzle needed)
#define XB_OFF   0ul          // 8388608
#define WALL_OFF 8388608ul    // 786432 (Wq^T*scale | Wk^T | Wv^T)
#define Q_OFF    9175040ul    // 16777216 (pre-scaled by log2e/sqrt(512))
#define K_OFF    25952256ul   // 16777216
#define VT_OFF   42729472ul   // 16777216
#define W2T_OFF  59506688ul   // 262144
#define S_OFF    59768832ul   // nb * 8388608

#define SCALE_Q 0.063758746f  // (1/sqrt(512)) * log2(e)

__device__ __forceinline__ unsigned short f2bf(float f) {
  unsigned u = __builtin_bit_cast(unsigned, f);
  return (unsigned short)((u + 0x7fffu + ((u >> 16) & 1u)) >> 16);  // RNE
}

__device__ __forceinline__ f32x4 mfma16(short8 a, short8 b, f32x4 c) {
  return __builtin_amdgcn_mfma_f32_16x16x32_bf16(
      __builtin_bit_cast(bf16x8, a), __builtin_bit_cast(bf16x8, b), c, 0, 0, 0);
}

__device__ __forceinline__ void glds16(const void* g, void* l) {
  __builtin_amdgcn_global_load_lds(
      (const __attribute__((address_space(1))) void*)g,
      (__attribute__((address_space(3))) void*)l, 16, 0, 0);
}

#define BAR_LGKM()                                           \
  {                                                          \
    asm volatile("s_waitcnt lgkmcnt(0)" ::: "memory");       \
    __builtin_amdgcn_sched_barrier(0);                       \
    __builtin_amdgcn_s_barrier();                            \
    __builtin_amdgcn_sched_barrier(0);                       \
  }
#define BAR_ALL()                                                    \
  {                                                                  \
    asm volatile("s_waitcnt vmcnt(0) lgkmcnt(0)" ::: "memory");      \
    __builtin_amdgcn_sched_barrier(0);                               \
    __builtin_amdgcn_s_barrier();                                    \
    __builtin_amdgcn_sched_barrier(0);                               \
  }

// ============================================================
// prep: bf16 conversions + transposes + swizzled layouts
// ============================================================
__global__ __launch_bounds__(256, 4) void prep_kernel(
    const float* __restrict__ feat, const float* __restrict__ Wq,
    const float* __restrict__ Wk, const float* __restrict__ Wv,
    const float* __restrict__ W2, char* __restrict__ ws) {
  int tid = blockIdx.x * 256 + threadIdx.x;
  if (tid < 524288) {  // Xb: 8-elem chunks
    int r = tid >> 5, co = (tid & 31) * 8;
    const float* src = feat + (size_t)r * 256 + co;
    short8 v;
#pragma unroll
    for (int i = 0; i < 8; ++i) v[i] = (short)f2bf(src[i]);
    unsigned short* Xb = (unsigned short*)(ws + XB_OFF);
    *(short8*)(Xb + (size_t)r * 256 + (co ^ ((r & 7) << 3))) = v;
  } else if (tid < 917504) {  // Wall[m][d] = W*[d][m] (scale folded into Wq)
    int t2 = tid - 524288;
    int m = t2 >> 8, d = t2 & 255;
    int wsel = m >> 9, mm = m & 511;
    const float* W = (wsel == 0) ? Wq : ((wsel == 1) ? Wk : Wv);
    float v = W[(size_t)d * 512 + mm];
    if (wsel == 0) v *= SCALE_Q;
    unsigned short* Wall = (unsigned short*)(ws + WALL_OFF);
    Wall[(size_t)m * 256 + (d ^ ((m & 7) << 3))] = f2bf(v);
  } else {  // W2t[d][c] = W2[c][d]  (LINEAR)
    int t3 = tid - 917504;
    int d = t3 >> 9, c = t3 & 511;
    unsigned short* W2t = (unsigned short*)(ws + W2T_OFF);
    W2t[(size_t)d * 512 + c] = f2bf(W2[(size_t)c * 256 + d]);
  }
}

// ============================================================
// proj: [16384,256] @ [256, 512*3] -> Q, K, Vt in TILED layouts
// 1536 blocks (XCD-chunked swizzle), 4 waves, 128x128 tile, BK=64 dbuf
// (R5-proven version)
// ============================================================
__global__ __launch_bounds__(256, 2) void proj_kernel(char* __restrict__ ws) {
  __shared__ char smem[65536];  // A dbuf 2x16KB @0, B dbuf 2x16KB @32768
  const int tid = threadIdx.x;
  const int l = tid & 63, w = tid >> 6;
  const int g = l >> 4, m16 = l & 15;
  const int orig = blockIdx.x;
  const int wgid = (orig & 7) * 192 + (orig >> 3);  // 1536%8==0, bijective
  const int nt = wgid % 12, mtb = wgid / 12;
  const char* XbT = ws + XB_OFF + (size_t)mtb * 65536;     // [128 r][512B]
  const char* WallT = ws + WALL_OFF + (size_t)nt * 65536;  // [128 r][512B]

  auto stage = [&](int buf, int kt) {
#pragma unroll
    for (int j = 0; j < 4; ++j) {
      int idx = j * 256 + tid;  // 0..1023: r=idx>>3, p=idx&7
      int r = idx >> 3, p = idx & 7;
      glds16(XbT + r * 512 + kt * 128 + p * 16, smem + buf * 16384 + idx * 16);
      glds16(WallT + r * 512 + kt * 128 + p * 16,
             smem + 32768 + buf * 16384 + idx * 16);
    }
  };

  const int mr = (w >> 1) * 64, nr = (w & 1) * 64;
  const int fxor = (m16 & 7) << 4;
  const f32x4 fz = {0.f, 0.f, 0.f, 0.f};
  f32x4 acc[4][4];
#pragma unroll
  for (int i = 0; i < 4; ++i)
#pragma unroll
    for (int j = 0; j < 4; ++j) acc[i][j] = fz;

  stage(0, 0);
  BAR_ALL();
#pragma unroll 1
  for (int kt = 0; kt < 4; ++kt) {
    if (kt < 3) stage((kt + 1) & 1, kt + 1);
    const char* Ab = smem + (kt & 1) * 16384;
    const char* Bb = smem + 32768 + (kt & 1) * 16384;
#pragma unroll
    for (int ks = 0; ks < 2; ++ks) {
      int off = (16 * g + 64 * ks) ^ fxor;
      short8 af[4], bf[4];
#pragma unroll
      for (int i = 0; i < 4; ++i)
        af[i] = *(const short8*)(Ab + (mr + i * 16 + m16) * 128 + off);
#pragma unroll
      for (int i = 0; i < 4; ++i)
        bf[i] = *(const short8*)(Bb + (nr + i * 16 + m16) * 128 + off);
#pragma unroll
      for (int mi = 0; mi < 4; ++mi)
#pragma unroll
        for (int ni = 0; ni < 4; ++ni)
          acc[mi][ni] = mfma16(af[mi], bf[ni], acc[mi][ni]);
    }
    BAR_ALL();
  }

  // ---- epilogue: per-wave repack buf [16][128B] ----
  const int colg = nt * 128 + nr;
  const int tcat = colg >> 9;       // 0=Q 1=K 2=V
  const int cin_base = colg & 511;  // col within tensor
  char* wbuf = smem + w * 2048;
  if (tcat < 2) {
    char* dst = ws + (tcat == 0 ? Q_OFF : K_OFF) +
                ((size_t)(mtb * 8 + (cin_base >> 6))) * 16384;
#pragma unroll
    for (int mi = 0; mi < 4; ++mi) {
#pragma unroll
      for (int ni = 0; ni < 4; ++ni)
#pragma unroll
        for (int j = 0; j < 4; ++j) {
          int r = g * 4 + j, c = ni * 16 + m16;
          *(unsigned short*)(wbuf + r * 128 + ((2 * c) ^ ((r & 7) << 4))) =
              f2bf(acc[mi][ni][j]);
        }
    asm volatile("s_waitcnt lgkmcnt(0)" ::: "memory");
    __builtin_amdgcn_sched_barrier(0);
#pragma unroll
      for (int s = 0; s < 2; ++s) {
        int cid = l + 64 * s;
        int r2 = cid >> 3, gi = cid & 7;
        short8 v = *(const short8*)(wbuf + r2 * 128 + gi * 16);
        int rt = mr + mi * 16 + r2;  // row in tile
        *(short8*)(dst + (size_t)rt * 128 + gi * 16) = v;
      }
    }
  } else {
    // V: gather column l per mi into registers, write each 128B row ONCE
    short8 grans[8];
#pragma unroll
    for (int mi = 0; mi < 4; ++mi) {
#pragma unroll
      for (int ni = 0; ni < 4; ++ni)
#pragma unroll
        for (int j = 0; j < 4; ++j) {
          int r = g * 4 + j, c = ni * 16 + m16;
          *(unsigned short*)(wbuf + r * 128 + ((2 * c) ^ ((r & 7) << 4))) =
              f2bf(acc[mi][ni][j]);
        }
      asm volatile("s_waitcnt lgkmcnt(0)" ::: "memory");
      __builtin_amdgcn_sched_barrier(0);
      unsigned short vals[16];
#pragma unroll
      for (int r2 = 0; r2 < 16; ++r2)
        vals[r2] = *(const unsigned short*)(wbuf + r2 * 128 +
                                            ((2 * l) ^ ((r2 & 7) << 4)));
      short8 v0, v1;
#pragma unroll
      for (int i2 = 0; i2 < 8; ++i2) {
        v0[i2] = (short)vals[i2];
        v1[i2] = (short)vals[8 + i2];
      }
      grans[2 * mi] = v0;      // true n-granule 2*mi
      grans[2 * mi + 1] = v1;  // true n-granule 2*mi+1
    }
    int cin = cin_base + l;
    int grow0 = mtb * 128 + mr;
    int bb = grow0 >> 11;
    int ktv = (grow0 & 2047) >> 6;
    char* vrow = ws + VT_OFF + (size_t)bb * 2097152 + (size_t)ktv * 65536 +
                 (size_t)cin * 128;
    const int fc = (cin & 7) << 4;
#pragma unroll
    for (int t = 0; t < 8; ++t)  // stored[p]=true[p^fc]
      *(short8*)(vrow + ((t * 16) ^ fc)) = grans[t];
  }
}

// ============================================================
// qk: S(f16, tiled) = Q @ K^T; 256 tiles/batch, 128x128, K=512, BK=64 dbuf
// LDS 64KB -> 2 blocks/CU; linear glds staging from tiled Q/K (R5 version)
// ============================================================
__global__ __launch_bounds__(256, 2) void qk_kernel(
    const char* __restrict__ ws, char* __restrict__ Sb, int nb, int b0) {
  __shared__ char smem[65536];  // A dbuf 2x16KB @0, B dbuf 2x16KB @32768
  const int tid = threadIdx.x;
  const int bid = blockIdx.x;
  const int z = bid % nb, tile = bid / nb;
  const int mt = tile >> 4, ntq = tile & 15;
  const int b = b0 + z;
  const int l = tid & 63, w = tid >> 6;
  const int g = l >> 4, m16 = l & 15;
  const int fxor = (m16 & 7) << 4;
  const char* Qt = ws + Q_OFF + (size_t)(b * 16 + mt) * 131072;
  const char* Kt = ws + K_OFF + (size_t)(b * 16 + ntq) * 131072;

  auto stage = [&](int buf, int kt) {
#pragma unroll
    for (int j = 0; j < 4; ++j) {
      int idx = j * 256 + tid;
      glds16(Qt + (size_t)kt * 16384 + idx * 16, smem + buf * 16384 + idx * 16);
      glds16(Kt + (size_t)kt * 16384 + idx * 16,
             smem + 32768 + buf * 16384 + idx * 16);
    }
  };

  const int mr = (w >> 1) * 64, nr = (w & 1) * 64;
  const f32x4 fz = {0.f, 0.f, 0.f, 0.f};
  f32x4 acc[4][4];
#pragma unroll
  for (int i = 0; i < 4; ++i)
#pragma unroll
    for (int j = 0; j < 4; ++j) acc[i][j] = fz;

  stage(0, 0);
  BAR_ALL();
#pragma unroll 1
  for (int kt = 0; kt < 8; ++kt) {
    if (kt < 7) stage((kt + 1) & 1, kt + 1);
    const char* Ab = smem + (kt & 1) * 16384;
    const char* Bb = smem + 32768 + (kt & 1) * 16384;
#pragma unroll
    for (int ks = 0; ks < 2; ++ks) {
      int off = (16 * g + 64 * ks) ^ fxor;
      short8 af[4], bf[4];
#pragma unroll
      for (int i = 0; i < 4; ++i)
        af[i] = *(const short8*)(Ab + (mr + i * 16 + m16) * 128 + off);
#pragma unroll
      for (int i = 0; i < 4; ++i)
        bf[i] = *(const short8*)(Bb + (nr + i * 16 + m16) * 128 + off);
#pragma unroll
      for (int mi = 0; mi < 4; ++mi)
#pragma unroll
        for (int ni = 0; ni < 4; ++ni)
          acc[mi][ni] = mfma16(af[mi], bf[ni], acc[mi][ni]);
    }
    BAR_ALL();
  }

  // ---- epilogue: f16 repack [128][272B] in LDS, then packed tiled stores --
#pragma unroll
  for (int mi = 0; mi < 4; ++mi)
#pragma unroll
    for (int ni = 0; ni < 4; ++ni)
#pragma unroll
      for (int j = 0; j < 4; ++j) {
        int r = mr + mi * 16 + g * 4 + j, c = nr + ni * 16 + m16;
        *(unsigned short*)(smem + r * 272 + 2 * c) =
            __builtin_bit_cast(unsigned short, (_Float16)acc[mi][ni][j]);
      }
  BAR_LGKM();
  char* Sbt = Sb + (size_t)z * 8388608;
#pragma unroll
  for (int it = 0; it < 8; ++it) {
    int idx = it * 256 + tid;
    int r = idx >> 4, gi = idx & 15;
    int rg = mt * 2 + (r >> 6), ck = ntq * 2 + (gi >> 3);
    *(short8*)(Sbt + ((size_t)(rg * 32 + ck) * 64 + (r & 63)) * 128 +
               (gi & 7) * 16) = *(const short8*)(smem + r * 272 + gi * 16);
  }
}

// ============================================================
// stats: row softmax on f16 S tiles; writes bf16 P in place, LINEAR
// granules (pv reads P direct to registers). One wave per row.
// ============================================================
__global__ __launch_bounds__(256, 8) void stats_kernel(char* __restrict__ Sb) {
  const int w = threadIdx.x >> 6, l = threadIdx.x & 63;
  const size_t row = (size_t)blockIdx.x * 4 + w;
  const int z = (int)(row >> 11), rloc = (int)(row & 2047);
  const int rg = rloc >> 6, r64 = rloc & 63;
  char* base = Sb + (size_t)z * 8388608 + (size_t)rg * 262144 +
               (size_t)r64 * 128;
  float sv[32];
#pragma unroll
  for (int i = 0; i < 4; ++i) {
    int idx = i * 64 + l;
    int ck = idx >> 3, gi = idx & 7;
    h8 hv = *(const h8*)(base + (size_t)ck * 8192 + gi * 16);
#pragma unroll
    for (int j = 0; j < 8; ++j) sv[i * 8 + j] = (float)hv[j];
  }
  float m = sv[0];
#pragma unroll
  for (int i = 1; i < 32; ++i) m = fmaxf(m, sv[i]);
  m = fmaxf(m, __shfl_xor(m, 1));
  m = fmaxf(m, __shfl_xor(m, 2));
  m = fmaxf(m, __shfl_xor(m, 4));
  m = fmaxf(m, __shfl_xor(m, 8));
  m = fmaxf(m, __shfl_xor(m, 16));
  m = fmaxf(m, __shfl_xor(m, 32));
  float sum = 0.f;
#pragma unroll
  for (int i = 0; i < 32; ++i) {
    float p = exp2f(sv[i] - m);
    sv[i] = p;
    sum += p;
  }
  sum += __shfl_xor(sum, 1);
  sum += __shfl_xor(sum, 2);
  sum += __shfl_xor(sum, 4);
  sum += __shfl_xor(sum, 8);
  sum += __shfl_xor(sum, 16);
  sum += __shfl_xor(sum, 32);
  const float rs = 1.0f / sum;
#pragma unroll
  for (int i = 0; i < 4; ++i) {
    int idx = i * 64 + l;
    int ck = idx >> 3, gi = idx & 7;
    short8 pk;
#pragma unroll
    for (int j = 0; j < 8; ++j) pk[j] = (short)f2bf(sv[i * 8 + j] * rs);
    *(short8*)(base + (size_t)ck * 8192 + gi * 16) = pk;  // LINEAR
  }
}

// ============================================================
// pv: O = P @ V, fused fc2/bias/leakyrelu/residual epilogue
// block = 64 q-rows x 512 v-cols; 512 thr, 8 waves (wave w: cols w*64..+64)
// K=2048 -> 32 kt of BK=64. P: DIRECT global->register (wave-uniform
// addresses -> L1 broadcast across 8 waves), double-buffered pA/pB.
// V: glds-staged dbuf 2x64KB. R5's single-BAR_ALL-per-kt schedule.
// ============================================================
__global__ __launch_bounds__(512) void pv_kernel(
    const char* __restrict__ ws, const char* __restrict__ Sb,
    const float* __restrict__ feat, const float* __restrict__ b2,
    float* __restrict__ out, int nb, int b0) {
  __shared__ char smem[131072];  // V dbuf 2x64KB (O epi overlays buf0)
  const int tid = threadIdx.x;
  const int bid = blockIdx.x;
  const int z = bid % nb, mt64 = bid / nb;  // z==XCD under bid%8 round-robin
  const int b = b0 + z;
  const int l = tid & 63, w = tid >> 6;
  const int g = l >> 4, m16 = l & 15;
  const int fxor = (m16 & 7) << 4;
  const char* Pr = Sb + (size_t)z * 8388608 + (size_t)mt64 * 262144;
  const char* Vt = ws + VT_OFF + (size_t)b * 2097152;

  const f32x4 fz = {0.f, 0.f, 0.f, 0.f};
  f32x4 acc[4][4];
#pragma unroll
  for (int i = 0; i < 4; ++i)
#pragma unroll
    for (int j = 0; j < 4; ++j) acc[i][j] = fz;

  auto stageV = [&](int buf, int kt) {  // 8 glds/thread, fully coalesced
#pragma unroll
    for (int j = 0; j < 8; ++j) {
      int idx = j * 512 + tid;
      glds16(Vt + (size_t)kt * 65536 + idx * 16,
             smem + buf * 65536 + idx * 16);
    }
  };
  auto loadP = [&](short8(&pf)[8], int kt) {  // wave-uniform -> L1 broadcast
    const char* Pk = Pr + (size_t)kt * 8192 + m16 * 128 + g * 16;
#pragma unroll
    for (int mi = 0; mi < 4; ++mi)
#pragma unroll
      for (int ks = 0; ks < 2; ++ks)
        pf[mi * 2 + ks] = *(const short8*)(Pk + mi * 2048 + ks * 64);
  };
  auto compute = [&](int buf, short8(&pf)[8]) {
    const char* Vb = smem + buf * 65536 + w * 8192;
#pragma unroll
    for (int ks = 0; ks < 2; ++ks) {
      int off = (16 * g + 64 * ks) ^ fxor;
      short8 vf[4];
#pragma unroll
      for (int i = 0; i < 4; ++i)
        vf[i] = *(const short8*)(Vb + (i * 16 + m16) * 128 + off);
#pragma unroll
      for (int mi = 0; mi < 4; ++mi)
#pragma unroll
        for (int ni = 0; ni < 4; ++ni)
          acc[mi][ni] = mfma16(pf[mi * 2 + ks], vf[ni], acc[mi][ni]);
    }
  };

  short8 pA[8], pB[8];
  loadP(pA, 0);
  stageV(0, 0);
  BAR_ALL();  // kt=0 data resident
#pragma unroll 1
  for (int kt2 = 0; kt2 < 16; ++kt2) {
    const int kt = kt2 * 2;
    if (kt + 1 < 32) {
      loadP(pB, kt + 1);
      stageV(1, kt + 1);
    }
    compute(0, pA);
    BAR_ALL();  // drain (kt+1) stage + sync buffers
    if (kt + 2 < 32) {
      loadP(pA, kt + 2);
      stageV(0, kt + 2);
    }
    compute(1, pB);
    BAR_ALL();
  }

  // ---- repack O (bf16, row-swizzled) into LDS [64][1024B] @0 ----
  char* Ob = smem;
#pragma unroll
  for (int mi = 0; mi < 4; ++mi)
#pragma unroll
    for (int ni = 0; ni < 4; ++ni)
#pragma unroll
      for (int j = 0; j < 4; ++j) {
        int r = mi * 16 + g * 4 + j;
        int c = w * 64 + ni * 16 + m16;
        *(unsigned short*)(Ob + r * 1024 + ((2 * c) ^ ((r & 7) << 4))) =
            f2bf(acc[mi][ni][j]);
      }
  BAR_LGKM();

  // ---- fc2: Y[64 x 256] = O @ W2 (+bias, lrelu, +residual) ----
  const char* W2g = ws + W2T_OFF;
  f32x4 y[4][2];
#pragma unroll
  for (int i = 0; i < 4; ++i) {
    y[i][0] = fz;
    y[i][1] = fz;
  }
#pragma unroll 1
  for (int ks = 0; ks < 16; ++ks) {
    int off = (ks * 64 + 16 * g);
    short8 aa[4], wb[2];
#pragma unroll
    for (int mi2 = 0; mi2 < 4; ++mi2) {
      int r = mi2 * 16 + m16;
      aa[mi2] = *(const short8*)(Ob + r * 1024 + (off ^ fxor));
    }
#pragma unroll
    for (int ni2 = 0; ni2 < 2; ++ni2) {
      int d = w * 32 + ni2 * 16 + m16;
      wb[ni2] = *(const short8*)(W2g + (size_t)d * 1024 + ks * 64 + g * 16);
    }
#pragma unroll
    for (int mi2 = 0; mi2 < 4; ++mi2)
#pragma unroll
      for (int ni2 = 0; ni2 < 2; ++ni2)
        y[mi2][ni2] = mfma16(aa[mi2], wb[ni2], y[mi2][ni2]);
  }
#pragma unroll
  for (int mi2 = 0; mi2 < 4; ++mi2)
#pragma unroll
    for (int ni2 = 0; ni2 < 2; ++ni2) {
      int d = w * 32 + ni2 * 16 + m16;
      float bias = b2[d];
#pragma unroll
      for (int j = 0; j < 4; ++j) {
        size_t gr = (size_t)b * 2048 + mt64 * 64 + mi2 * 16 + g * 4 + j;
        float v = y[mi2][ni2][j] + bias;
        v = v > 0.f ? v : 0.2f * v;
        out[gr * 256 + d] = v + feat[gr * 256 + d];
      }
    }
}

// ============================================================
extern "C" void kernel_launch(void* const* d_in, const int* in_sizes, int n_in,
                              void* d_out, int out_size, void* d_ws, size_t ws_size,
                              hipStream_t stream) {
  const float* feat = (const float*)d_in[0];
  const float* Wq = (const float*)d_in[1];
  const float* Wk = (const float*)d_in[2];
  const float* Wv = (const float*)d_in[3];
  const float* W2 = (const float*)d_in[4];
  const float* b2 = (const float*)d_in[5];
  float* out = (float*)d_out;
  char* ws = (char*)d_ws;
  (void)in_sizes; (void)n_in; (void)out_size;

  prep_kernel<<<4096, 256, 0, stream>>>(feat, Wq, Wk, Wv, W2, ws);
  proj_kernel<<<1536, 256, 0, stream>>>(ws);

  const size_t per_batch = 8388608ul;  // f16/bf16 S: 2048 rows * 4096 B
  int nb = 8;
  while (nb > 1 && S_OFF + (size_t)nb * per_batch > ws_size) nb >>= 1;
  char* Sb = ws + S_OFF;
  for (int b0 = 0; b0 < 8; b0 += nb) {
    qk_kernel<<<256 * nb, 256, 0, stream>>>(ws, Sb, nb, b0);
    stats_kernel<<<512 * nb, 256, 0, stream>>>(Sb);
    pv_kernel<<<32 * nb, 512, 0, stream>>>(ws, Sb, feat, b2, out, nb, b0);
  }
}

// Round 11
// 177.425 us; speedup vs baseline: 1.2338x; 1.1550x over previous
//
#include <hip/hip_runtime.h>
#include <cstdint>

// ---------------- problem constants ----------------
// features [8,2048,256] f32; Wq/Wk/Wv [256,512]; W2 [512,256]; b2 [256]
// out [8,2048,256] f32
#define NBATCH 8
#define NSEQ   2048
#define NROWS  16384

typedef __attribute__((ext_vector_type(4))) float  f32x4;
typedef __attribute__((ext_vector_type(8))) short  short8;
typedef __attribute__((ext_vector_type(8))) __bf16 bf16x8;
typedef __attribute__((ext_vector_type(8))) _Float16 h8;

// ---------------- workspace layout (bytes) ----------------
// Xb/Wall: row-granule-swizzled bf16 (granule ^= row&7) -- glds-staged
// Q/K : TILED [t 128][ck 8][r 128][128B], granules stored[p]=true[p^(r&7)]
// Vt  : FRAG-ORDER [b][kt32 64][w' 8][ni 4][lane 64][16B]
//       element (k,c): lane=(c&15)+16*((k&31)>>3), e=k&7  (B-frag linear)
// W2t : TILED like Q/K: [t 2][ck 8][r 128][128B], granules p^(r&7)
// O   : TILED like Q/K: [t 128][ck 8][r 128][128B], granules p^(r&7)
// RS  : [b 8][2048] f32  (1/softmax-denominator per row)
// S/P : FRAG-ORDER per batch-slot z: [rg 32][kt32 64][mi 4][lane 64][16B]
//       element (r,k): mi=(r&63)>>4, lane=(r&15)+16*((k&31)>>3), e=k&7
//       qk writes f16 S; stats overwrites in place with bf16 exp2(s-12)
#define XB_OFF   0ul          // 8388608
#define WALL_OFF 8388608ul    // 786432 (Wq^T*scale | Wk^T | Wv^T)
#define Q_OFF    9175040ul    // 16777216 (pre-scaled by log2e/sqrt(512))
#define K_OFF    25952256ul   // 16777216
#define VT_OFF   42729472ul   // 16777216
#define W2T_OFF  59506688ul   // 262144
#define O_OFF    59768832ul   // 16777216
#define RS_OFF   76546048ul   // 65536
#define S_OFF    76611584ul   // nb * 8388608

#define SCALE_Q 0.063758746f  // (1/sqrt(512)) * log2(e)
#define FIXMAX  12.0f         // fixed softmax max (log2 domain); rs renormalizes

__device__ __forceinline__ unsigned short f2bf(float f) {
  unsigned u = __builtin_bit_cast(unsigned, f);
  return (unsigned short)((u + 0x7fffu + ((u >> 16) & 1u)) >> 16);  // RNE
}

__device__ __forceinline__ f32x4 mfma16(short8 a, short8 b, f32x4 c) {
  return __builtin_amdgcn_mfma_f32_16x16x32_bf16(
      __builtin_bit_cast(bf16x8, a), __builtin_bit_cast(bf16x8, b), c, 0, 0, 0);
}

__device__ __forceinline__ void glds16(const void* g, void* l) {
  __builtin_amdgcn_global_load_lds(
      (const __attribute__((address_space(1))) void*)g,
      (__attribute__((address_space(3))) void*)l, 16, 0, 0);
}

#define BAR_SYNC()                     \
  {                                    \
    __builtin_amdgcn_sched_barrier(0); \
    __builtin_amdgcn_s_barrier();      \
    __builtin_amdgcn_sched_barrier(0); \
  }
#define BAR_LGKM()                                           \
  {                                                          \
    asm volatile("s_waitcnt lgkmcnt(0)" ::: "memory");       \
    __builtin_amdgcn_sched_barrier(0);                       \
    __builtin_amdgcn_s_barrier();                            \
    __builtin_amdgcn_sched_barrier(0);                       \
  }
#define BAR_ALL()                                                    \
  {                                                                  \
    asm volatile("s_waitcnt vmcnt(0) lgkmcnt(0)" ::: "memory");      \
    __builtin_amdgcn_sched_barrier(0);                               \
    __builtin_amdgcn_s_barrier();                                    \
    __builtin_amdgcn_sched_barrier(0);                               \
  }
#define WAITV(N)                                                  \
  {                                                               \
    __builtin_amdgcn_sched_barrier(0);                            \
    asm volatile("s_waitcnt vmcnt(" #N ")" ::: "memory");         \
    __builtin_amdgcn_sched_barrier(0);                            \
  }

// ============================================================
// prep: bf16 conversions + transposes + tiled layouts
// ============================================================
__global__ __launch_bounds__(256, 4) void prep_kernel(
    const float* __restrict__ feat, const float* __restrict__ Wq,
    const float* __restrict__ Wk, const float* __restrict__ Wv,
    const float* __restrict__ W2, char* __restrict__ ws) {
  int tid = blockIdx.x * 256 + threadIdx.x;
  if (tid < 524288) {  // Xb: 8-elem chunks
    int r = tid >> 5, co = (tid & 31) * 8;
    const float* src = feat + (size_t)r * 256 + co;
    short8 v;
#pragma unroll
    for (int i = 0; i < 8; ++i) v[i] = (short)f2bf(src[i]);
    unsigned short* Xb = (unsigned short*)(ws + XB_OFF);
    *(short8*)(Xb + (size_t)r * 256 + (co ^ ((r & 7) << 3))) = v;
  } else if (tid < 917504) {  // Wall[m][d] = W*[d][m] (scale folded into Wq)
    int t2 = tid - 524288;
    int m = t2 >> 8, d = t2 & 255;
    int wsel = m >> 9, mm = m & 511;
    const float* W = (wsel == 0) ? Wq : ((wsel == 1) ? Wk : Wv);
    float v = W[(size_t)d * 512 + mm];
    if (wsel == 0) v *= SCALE_Q;
    unsigned short* Wall = (unsigned short*)(ws + WALL_OFF);
    Wall[(size_t)m * 256 + (d ^ ((m & 7) << 3))] = f2bf(v);
  } else {  // W2t TILED [t 2][ck 8][r 128][128B], granules p = gt ^ (r&7)
    int t3 = tid - 917504;
    int d = t3 >> 9, c = t3 & 511;
    int r = d & 127;
    size_t addr = (size_t)((d >> 7) * 8 + (c >> 6)) * 16384 + (size_t)r * 128 +
                  (size_t)((((c >> 3) & 7) ^ (r & 7)) * 16) + (c & 7) * 2;
    *(unsigned short*)(ws + W2T_OFF + addr) = f2bf(W2[(size_t)c * 256 + d]);
  }
}

// ============================================================
// proj: [16384,256] @ [256, 512*3] -> Q/K (tiled swz), Vt (frag-order)
// 1536 blocks (XCD-chunked swizzle), 4 waves, 128x128 tile, BK=64 dbuf
// ============================================================
__global__ __launch_bounds__(256, 2) void proj_kernel(char* __restrict__ ws) {
  __shared__ char smem[65536];  // A dbuf 2x16KB @0, B dbuf 2x16KB @32768
  const int tid = threadIdx.x;
  const int l = tid & 63, w = tid >> 6;
  const int g = l >> 4, m16 = l & 15;
  const int orig = blockIdx.x;
  const int wgid = (orig & 7) * 192 + (orig >> 3);  // bijective (1536%8==0)
  const int nt = wgid % 12, mtb = wgid / 12;
  const char* XbT = ws + XB_OFF + (size_t)mtb * 65536;     // [128 r][512B]
  const char* WallT = ws + WALL_OFF + (size_t)nt * 65536;  // [128 r][512B]

  auto stage = [&](int buf, int kt) {
#pragma unroll
    for (int j = 0; j < 4; ++j) {
      int idx = j * 256 + tid;  // r=idx>>3, p=idx&7
      int r = idx >> 3, p = idx & 7;
      glds16(XbT + r * 512 + kt * 128 + p * 16, smem + buf * 16384 + idx * 16);
      glds16(WallT + r * 512 + kt * 128 + p * 16,
             smem + 32768 + buf * 16384 + idx * 16);
    }
  };

  const int mr = (w >> 1) * 64, nr = (w & 1) * 64;
  const int fxor = (m16 & 7) << 4;
  const f32x4 fz = {0.f, 0.f, 0.f, 0.f};
  f32x4 acc[4][4];
#pragma unroll
  for (int i = 0; i < 4; ++i)
#pragma unroll
    for (int j = 0; j < 4; ++j) acc[i][j] = fz;

  stage(0, 0);
  BAR_ALL();
#pragma unroll 1
  for (int kt = 0; kt < 4; ++kt) {
    if (kt < 3) stage((kt + 1) & 1, kt + 1);
    const char* Ab = smem + (kt & 1) * 16384;
    const char* Bb = smem + 32768 + (kt & 1) * 16384;
#pragma unroll
    for (int ks = 0; ks < 2; ++ks) {
      int off = (16 * g + 64 * ks) ^ fxor;
      short8 af[4], bf[4];
#pragma unroll
      for (int i = 0; i < 4; ++i)
        af[i] = *(const short8*)(Ab + (mr + i * 16 + m16) * 128 + off);
#pragma unroll
      for (int i = 0; i < 4; ++i)
        bf[i] = *(const short8*)(Bb + (nr + i * 16 + m16) * 128 + off);
#pragma unroll
      for (int mi = 0; mi < 4; ++mi)
#pragma unroll
        for (int ni = 0; ni < 4; ++ni)
          acc[mi][ni] = mfma16(af[mi], bf[ni], acc[mi][ni]);
    }
    BAR_ALL();
  }

  // ---- epilogue ----
  const int colg = nt * 128 + nr;
  const int tcat = colg >> 9;       // 0=Q 1=K 2=V
  const int cin_base = colg & 511;  // col within tensor
  char* wbuf = smem + w * 2048;     // per-wave [16][128B]
  if (tcat < 2) {
    char* dst = ws + (tcat == 0 ? Q_OFF : K_OFF) +
                ((size_t)(mtb * 8 + (cin_base >> 6))) * 16384;
#pragma unroll
    for (int mi = 0; mi < 4; ++mi) {
#pragma unroll
      for (int ni = 0; ni < 4; ++ni)
#pragma unroll
        for (int j = 0; j < 4; ++j) {
          int r = g * 4 + j, c = ni * 16 + m16;
          *(unsigned short*)(wbuf + r * 128 + ((2 * c) ^ ((r & 7) << 4))) =
              f2bf(acc[mi][ni][j]);
        }
      asm volatile("s_waitcnt lgkmcnt(0)" ::: "memory");
      __builtin_amdgcn_sched_barrier(0);
#pragma unroll
      for (int s = 0; s < 2; ++s) {
        int cid = l + 64 * s;
        int r2 = cid >> 3, gi = cid & 7;
        short8 v = *(const short8*)(wbuf + r2 * 128 + gi * 16);
        int rt = mr + mi * 16 + r2;  // row in tile
        *(short8*)(dst + (size_t)rt * 128 + gi * 16) = v;
      }
    }
  } else {
    // V: gather column l per mi; write FRAG-ORDER Vt granules
    int cin = cin_base + l;
    int grow0 = mtb * 128 + mr;
    int z2 = grow0 >> 11;
    int k0 = (grow0 & 2047) >> 5;
    char* vbase = ws + VT_OFF + (size_t)z2 * 2097152 +
                  (size_t)(cin >> 6) * 4096 + (size_t)((cin >> 4) & 3) * 1024 +
                  (size_t)(cin & 15) * 16;
#pragma unroll
    for (int mi = 0; mi < 4; ++mi) {
#pragma unroll
      for (int ni = 0; ni < 4; ++ni)
#pragma unroll
        for (int j = 0; j < 4; ++j) {
          int r = g * 4 + j, c = ni * 16 + m16;
          *(unsigned short*)(wbuf + r * 128 + ((2 * c) ^ ((r & 7) << 4))) =
              f2bf(acc[mi][ni][j]);
        }
      asm volatile("s_waitcnt lgkmcnt(0)" ::: "memory");
      __builtin_amdgcn_sched_barrier(0);
      unsigned short vals[16];
#pragma unroll
      for (int r2 = 0; r2 < 16; ++r2)
        vals[r2] = *(const unsigned short*)(wbuf + r2 * 128 +
                                            ((2 * l) ^ ((r2 & 7) << 4)));
      short8 v0, v1;
#pragma unroll
      for (int i2 = 0; i2 < 8; ++i2) {
        v0[i2] = (short)vals[i2];
        v1[i2] = (short)vals[8 + i2];
      }
      int kt32 = k0 + (mi >> 1);
      int gb = (mi & 1) * 2;
      *(short8*)(vbase + (size_t)kt32 * 32768 + gb * 256) = v0;
      *(short8*)(vbase + (size_t)kt32 * 32768 + (gb + 1) * 256) = v1;
    }
  }
}

// ============================================================
// qk: S(f16, FRAG-ORDER) = Q @ K^T; 128x128 tiles, K=512, BK=64 dbuf
// (R5-proven main loop; only the store addressing changed)
// ============================================================
__global__ __launch_bounds__(256, 2) void qk_kernel(
    const char* __restrict__ ws, char* __restrict__ Sb, int nb, int b0) {
  __shared__ char smem[65536];  // A dbuf 2x16KB @0, B dbuf 2x16KB @32768
  const int tid = threadIdx.x;
  const int bid = blockIdx.x;
  const int z = bid % nb, tile = bid / nb;
  const int mt = tile >> 4, ntq = tile & 15;
  const int b = b0 + z;
  const int l = tid & 63, w = tid >> 6;
  const int g = l >> 4, m16 = l & 15;
  const int fxor = (m16 & 7) << 4;
  const char* Qt = ws + Q_OFF + (size_t)(b * 16 + mt) * 131072;
  const char* Kt = ws + K_OFF + (size_t)(b * 16 + ntq) * 131072;

  auto stage = [&](int buf, int kt) {
#pragma unroll
    for (int j = 0; j < 4; ++j) {
      int idx = j * 256 + tid;
      glds16(Qt + (size_t)kt * 16384 + idx * 16, smem + buf * 16384 + idx * 16);
      glds16(Kt + (size_t)kt * 16384 + idx * 16,
             smem + 32768 + buf * 16384 + idx * 16);
    }
  };

  const int mr = (w >> 1) * 64, nr = (w & 1) * 64;
  const f32x4 fz = {0.f, 0.f, 0.f, 0.f};
  f32x4 acc[4][4];
#pragma unroll
  for (int i = 0; i < 4; ++i)
#pragma unroll
    for (int j = 0; j < 4; ++j) acc[i][j] = fz;

  stage(0, 0);
  BAR_ALL();
#pragma unroll 1
  for (int kt = 0; kt < 8; ++kt) {
    if (kt < 7) stage((kt + 1) & 1, kt + 1);
    const char* Ab = smem + (kt & 1) * 16384;
    const char* Bb = smem + 32768 + (kt & 1) * 16384;
#pragma unroll
    for (int ks = 0; ks < 2; ++ks) {
      int off = (16 * g + 64 * ks) ^ fxor;
      short8 af[4], bf[4];
#pragma unroll
      for (int i = 0; i < 4; ++i)
        af[i] = *(const short8*)(Ab + (mr + i * 16 + m16) * 128 + off);
#pragma unroll
      for (int i = 0; i < 4; ++i)
        bf[i] = *(const short8*)(Bb + (nr + i * 16 + m16) * 128 + off);
#pragma unroll
      for (int mi = 0; mi < 4; ++mi)
#pragma unroll
        for (int ni = 0; ni < 4; ++ni)
          acc[mi][ni] = mfma16(af[mi], bf[ni], acc[mi][ni]);
    }
    BAR_ALL();
  }

  // ---- epilogue: f16 repack [128][272B] in LDS, frag-order linear stores --
#pragma unroll
  for (int mi = 0; mi < 4; ++mi)
#pragma unroll
    for (int ni = 0; ni < 4; ++ni)
#pragma unroll
      for (int j = 0; j < 4; ++j) {
        int r = mr + mi * 16 + g * 4 + j, c = nr + ni * 16 + m16;
        *(unsigned short*)(smem + r * 272 + 2 * c) =
            __builtin_bit_cast(unsigned short, (_Float16)acc[mi][ni][j]);
      }
  BAR_LGKM();
  char* Sz = Sb + (size_t)z * 8388608;
#pragma unroll
  for (int it = 0; it < 8; ++it) {
    int idx = it * 256 + tid;
    int rgh = idx >> 10, rem = idx & 1023;
    int kt32L = rem >> 8, rem2 = rem & 255;
    int mi2 = rem2 >> 6, lslot = rem2 & 63;
    int row = rgh * 64 + mi2 * 16 + (lslot & 15);
    int bcol = kt32L * 64 + (lslot >> 4) * 16;
    short8 v = *(const short8*)(smem + row * 272 + bcol);
    *(short8*)(Sz + (size_t)(mt * 2 + rgh) * 262144 +
               (size_t)(ntq * 4 + kt32L) * 4096 + mi2 * 1024 + lslot * 16) = v;
  }
}

// ============================================================
// stats: single-pass fixed-max softmax transform, in place.
// Block = one (z, rg 64-row group). P_unnorm = exp2(s - 12) bf16;
// rs[row] = 1/sum written to RS table (applied in pv epilogue).
// thread t: row=((t>>6)&3)*16+(t&15); granules L = i*256+t (coalesced)
// ============================================================
__global__ __launch_bounds__(256, 2) void stats_kernel(
    char* __restrict__ Sb, float* __restrict__ rs_out, int nb, int b0) {
  const int tid = threadIdx.x;
  const int bid = blockIdx.x;
  const int z = bid % nb, rg = bid / nb;
  char* R = Sb + (size_t)z * 8388608 + (size_t)rg * 262144;
  float sum = 0.f;
#pragma unroll 4
  for (int i = 0; i < 64; ++i) {
    char* p = R + ((size_t)i * 256 + tid) * 16;
    h8 hv = *(const h8*)p;
    short8 pk;
#pragma unroll
    for (int j = 0; j < 8; ++j) {
      float e = exp2f((float)hv[j] - FIXMAX);
      sum += e;
      pk[j] = (short)f2bf(e);
    }
    *(short8*)p = pk;
  }
  sum += __shfl_xor(sum, 16);
  sum += __shfl_xor(sum, 32);
  if ((tid & 48) == 0) {
    int myrow = ((tid >> 6) & 3) * 16 + (tid & 15);
    rs_out[(size_t)(b0 + z) * 2048 + rg * 64 + myrow] = 1.0f / sum;
  }
}

// ============================================================
// pv: O = P_unnorm @ V, rs-normalized at epilogue, O -> ws (tiled)
// block = 64 rows x 256 cols (cb half); 4 waves (wave w: 64 cols)
// BK=32, 64 kt; P direct global->regs (coalesced frag-order, dbuf pA/pB);
// V glds linear frag-order dbuf 2x16KB; counted WAITV(8).
// ============================================================
__global__ __launch_bounds__(256, 2) void pv_kernel(
    char* __restrict__ ws, char* __restrict__ Sb, int nb, int b0) {
  __shared__ char smem[32768];  // V dbuf 2x16KB; epilogue wbuf overlays
  const int tid = threadIdx.x;
  const int bid = blockIdx.x;
  const int z = bid % nb, tile = bid / nb;
  const int cb = tile & 1, mt64 = tile >> 1;  // cb: col half, mt64: row block
  const int b = b0 + z;
  const int l = tid & 63, w = tid >> 6;
  const int g = l >> 4, m16 = l & 15;
  const char* Pr = Sb + (size_t)z * 8388608 + (size_t)mt64 * 262144;
  const char* Vt = ws + VT_OFF + (size_t)b * 2097152 + (size_t)cb * 16384;

  const f32x4 fz = {0.f, 0.f, 0.f, 0.f};
  f32x4 acc[4][4];
#pragma unroll
  for (int i = 0; i < 4; ++i)
#pragma unroll
    for (int j = 0; j < 4; ++j) acc[i][j] = fz;

  auto loadP = [&](short8(&pf)[4], int kt) {
    const char* p = Pr + (size_t)kt * 4096 + l * 16;
#pragma unroll
    for (int mi = 0; mi < 4; ++mi)
      pf[mi] = *(const short8*)(p + mi * 1024);
  };
  auto stageV = [&](int buf, int kt) {
#pragma unroll
    for (int j = 0; j < 4; ++j) {
      int idx = j * 256 + tid;
      glds16(Vt + (size_t)kt * 32768 + idx * 16, smem + buf * 16384 + idx * 16);
    }
  };
  auto compute = [&](int buf, short8(&pf)[4]) {
    const char* Vb = smem + buf * 16384 + w * 4096 + l * 16;
    short8 vf[4];
#pragma unroll
    for (int ni = 0; ni < 4; ++ni) vf[ni] = *(const short8*)(Vb + ni * 1024);
#pragma unroll
    for (int mi = 0; mi < 4; ++mi)
#pragma unroll
      for (int ni = 0; ni < 4; ++ni)
        acc[mi][ni] = mfma16(pf[mi], vf[ni], acc[mi][ni]);
  };

  short8 pA[4], pB[4];
  loadP(pA, 0);
  stageV(0, 0);
  WAITV(0);
  BAR_SYNC();
#pragma unroll 1
  for (int kt2 = 0; kt2 < 32; ++kt2) {
    const int kt = kt2 * 2;
    // half 1: compute kt (buf0, pA); prefetch kt+1
    loadP(pB, kt + 1);
    stageV(1, kt + 1);
    WAITV(8);
    BAR_SYNC();
    compute(0, pA);
    BAR_LGKM();
    // half 2: compute kt+1 (buf1, pB); prefetch kt+2
    if (kt + 2 < 64) {
      loadP(pA, kt + 2);
      stageV(0, kt + 2);
      WAITV(8);
    } else {
      WAITV(0);
    }
    BAR_SYNC();
    compute(1, pB);
    BAR_LGKM();
  }

  // ---- rs-normalize, then store O (bf16, Q-style tiled) ----
  const float* rsp = (const float*)(ws + RS_OFF) + (size_t)b * 2048 + mt64 * 64;
#pragma unroll
  for (int mi = 0; mi < 4; ++mi) {
    f32x4 rv;
#pragma unroll
    for (int j = 0; j < 4; ++j) rv[j] = rsp[mi * 16 + g * 4 + j];
#pragma unroll
    for (int ni = 0; ni < 4; ++ni) acc[mi][ni] *= rv;
  }
  char* wbuf = smem + w * 2048;  // per-wave [16][128B]
  const int tI = b * 16 + (mt64 >> 1);
  char* dst = ws + O_OFF + ((size_t)tI * 8 + cb * 4 + w) * 16384 +
              (size_t)(mt64 & 1) * 8192;
#pragma unroll 1
  for (int mi = 0; mi < 4; ++mi) {
#pragma unroll
    for (int ni = 0; ni < 4; ++ni)
#pragma unroll
      for (int j = 0; j < 4; ++j) {
        int r = g * 4 + j, c = ni * 16 + m16;
        *(unsigned short*)(wbuf + r * 128 + ((2 * c) ^ ((r & 7) << 4))) =
            f2bf(acc[mi][ni][j]);
      }
    asm volatile("s_waitcnt lgkmcnt(0)" ::: "memory");
    __builtin_amdgcn_sched_barrier(0);
#pragma unroll
    for (int s = 0; s < 2; ++s) {
      int cid = l + 64 * s;
      int r2 = cid >> 3, gi = cid & 7;
      short8 v = *(const short8*)(wbuf + r2 * 128 + gi * 16);
      *(short8*)(dst + (size_t)(mi * 16 + r2) * 128 + gi * 16) = v;
    }
  }
}

// ============================================================
// fc2: out = lrelu(O @ W2 + b2) + feat ; qk-clone structure
// grid 256: mtF = bid>>1 (128 row-tiles), ntF = bid&1 (2 col-tiles)
// ============================================================
__global__ __launch_bounds__(256, 2) void fc2_kernel(
    const char* __restrict__ ws, const float* __restrict__ feat,
    const float* __restrict__ b2, float* __restrict__ out) {
  __shared__ char smem[65536];  // A dbuf 2x16KB @0, B dbuf 2x16KB @32768
  const int tid = threadIdx.x;
  const int mtF = blockIdx.x >> 1, ntF = blockIdx.x & 1;
  const int l = tid & 63, w = tid >> 6;
  const int g = l >> 4, m16 = l & 15;
  const int fxor = (m16 & 7) << 4;
  const char* At = ws + O_OFF + (size_t)mtF * 131072;
  const char* Bt = ws + W2T_OFF + (size_t)ntF * 131072;

  auto stage = [&](int buf, int kt) {
#pragma unroll
    for (int j = 0; j < 4; ++j) {
      int idx = j * 256 + tid;
      glds16(At + (size_t)kt * 16384 + idx * 16, smem + buf * 16384 + idx * 16);
      glds16(Bt + (size_t)kt * 16384 + idx * 16,
             smem + 32768 + buf * 16384 + idx * 16);
    }
  };

  const int mr = (w >> 1) * 64, nr = (w & 1) * 64;
  const f32x4 fz = {0.f, 0.f, 0.f, 0.f};
  f32x4 acc[4][4];
#pragma unroll
  for (int i = 0; i < 4; ++i)
#pragma unroll
    for (int j = 0; j < 4; ++j) acc[i][j] = fz;

  stage(0, 0);
  BAR_ALL();
#pragma unroll 1
  for (int kt = 0; kt < 8; ++kt) {
    if (kt < 7) stage((kt + 1) & 1, kt + 1);
    const char* Ab = smem + (kt & 1) * 16384;
    const char* Bb = smem + 32768 + (kt & 1) * 16384;
#pragma unroll
    for (int ks = 0; ks < 2; ++ks) {
      int off = (16 * g + 64 * ks) ^ fxor;
      short8 af[4], bf[4];
#pragma unroll
      for (int i = 0; i < 4; ++i)
        af[i] = *(const short8*)(Ab + (mr + i * 16 + m16) * 128 + off);
#pragma unroll
      for (int i = 0; i < 4; ++i)
        bf[i] = *(const short8*)(Bb + (nr + i * 16 + m16) * 128 + off);
#pragma unroll
      for (int mi = 0; mi < 4; ++mi)
#pragma unroll
        for (int ni = 0; ni < 4; ++ni)
          acc[mi][ni] = mfma16(af[mi], bf[ni], acc[mi][ni]);
    }
    BAR_ALL();
  }

  // ---- epilogue: bias + leakyrelu + residual, f32 stores ----
#pragma unroll
  for (int mi = 0; mi < 4; ++mi)
#pragma unroll
    for (int ni = 0; ni < 4; ++ni) {
      int d = ntF * 128 + nr + ni * 16 + m16;
      float bias = b2[d];
#pragma unroll
      for (int j = 0; j < 4; ++j) {
        size_t m = (size_t)mtF * 128 + mr + mi * 16 + g * 4 + j;
        float v = acc[mi][ni][j] + bias;
        v = v > 0.f ? v : 0.2f * v;
        out[m * 256 + d] = v + feat[m * 256 + d];
      }
    }
}

// ============================================================
extern "C" void kernel_launch(void* const* d_in, const int* in_sizes, int n_in,
                              void* d_out, int out_size, void* d_ws, size_t ws_size,
                              hipStream_t stream) {
  const float* feat = (const float*)d_in[0];
  const float* Wq = (const float*)d_in[1];
  const float* Wk = (const float*)d_in[2];
  const float* Wv = (const float*)d_in[3];
  const float* W2 = (const float*)d_in[4];
  const float* b2 = (const float*)d_in[5];
  float* out = (float*)d_out;
  char* ws = (char*)d_ws;
  (void)in_sizes; (void)n_in; (void)out_size;

  prep_kernel<<<4096, 256, 0, stream>>>(feat, Wq, Wk, Wv, W2, ws);
  proj_kernel<<<1536, 256, 0, stream>>>(ws);

  const size_t per_batch = 8388608ul;  // S/P: 2048 rows * 4096 B
  int nb = 8;
  while (nb > 1 && S_OFF + (size_t)nb * per_batch > ws_size) nb >>= 1;
  char* Sb = ws + S_OFF;
  float* rs = (float*)(ws + RS_OFF);
  for (int b0 = 0; b0 < 8; b0 += nb) {
    qk_kernel<<<256 * nb, 256, 0, stream>>>(ws, Sb, nb, b0);
    stats_kernel<<<32 * nb, 256, 0, stream>>>(Sb, rs, nb, b0);
    pv_kernel<<<64 * nb, 256, 0, stream>>>(ws, Sb, nb, b0);
  }
  fc2_kernel<<<256, 256, 0, stream>>>(ws, feat, b2, out);
}

// Round 12
// 177.020 us; speedup vs baseline: 1.2366x; 1.0023x over previous
//
#include <hip/hip_runtime.h>
#include <cstdint>

// ---------------- problem constants ----------------
// features [8,2048,256] f32; Wq/Wk/Wv [256,512]; W2 [512,256]; b2 [256]
// out [8,2048,256] f32
#define NBATCH 8
#define NSEQ   2048
#define NROWS  16384

typedef __attribute__((ext_vector_type(4))) float  f32x4;
typedef __attribute__((ext_vector_type(8))) short  short8;
typedef __attribute__((ext_vector_type(8))) __bf16 bf16x8;
typedef __attribute__((ext_vector_type(8))) _Float16 h8;

// ---------------- workspace layout (bytes) ----------------
// Xb/Wall: row-granule-swizzled bf16 (granule ^= row&7) -- glds-staged
// Q/K : TILED [t 128][ck 8][r 128][128B], granules stored[p]=true[p^(r&7)]
// Vt  : FRAG-ORDER [b][kt32 64][w' 8][ni 4][lane 64][16B]
// W2t : TILED like Q/K: [t 2][ck 8][r 128][128B], granules p^(r&7)
// O   : TILED like Q/K: [t 128][ck 8][r 128][128B], granules p^(r&7)
// RS  : [b 8][2048] f32  (1/softmax-denominator per row)
// S/P : FRAG-ORDER per batch-slot z: [rg 32][kt32 64][mi 4][lane 64][16B]
//       qk writes f16 S; stats overwrites in place with bf16 exp2(s-12)
#define XB_OFF   0ul          // 8388608
#define WALL_OFF 8388608ul    // 786432 (Wq^T*scale | Wk^T | Wv^T)
#define Q_OFF    9175040ul    // 16777216 (pre-scaled by log2e/sqrt(512))
#define K_OFF    25952256ul   // 16777216
#define VT_OFF   42729472ul   // 16777216
#define W2T_OFF  59506688ul   // 262144
#define O_OFF    59768832ul   // 16777216
#define RS_OFF   76546048ul   // 65536
#define S_OFF    76611584ul   // nb * 8388608

#define SCALE_Q 0.063758746f  // (1/sqrt(512)) * log2(e)
#define FIXMAX  12.0f         // fixed softmax max (log2 domain); rs renormalizes

__device__ __forceinline__ unsigned short f2bf(float f) {
  unsigned u = __builtin_bit_cast(unsigned, f);
  return (unsigned short)((u + 0x7fffu + ((u >> 16) & 1u)) >> 16);  // RNE
}

__device__ __forceinline__ f32x4 mfma16(short8 a, short8 b, f32x4 c) {
  return __builtin_amdgcn_mfma_f32_16x16x32_bf16(
      __builtin_bit_cast(bf16x8, a), __builtin_bit_cast(bf16x8, b), c, 0, 0, 0);
}

__device__ __forceinline__ void glds16(const void* g, void* l) {
  __builtin_amdgcn_global_load_lds(
      (const __attribute__((address_space(1))) void*)g,
      (__attribute__((address_space(3))) void*)l, 16, 0, 0);
}

#define BAR_SYNC()                     \
  {                                    \
    __builtin_amdgcn_sched_barrier(0); \
    __builtin_amdgcn_s_barrier();      \
    __builtin_amdgcn_sched_barrier(0); \
  }
#define BAR_LGKM()                                           \
  {                                                          \
    asm volatile("s_waitcnt lgkmcnt(0)" ::: "memory");       \
    __builtin_amdgcn_sched_barrier(0);                       \
    __builtin_amdgcn_s_barrier();                            \
    __builtin_amdgcn_sched_barrier(0);                       \
  }
#define BAR_ALL()                                                    \
  {                                                                  \
    asm volatile("s_waitcnt vmcnt(0) lgkmcnt(0)" ::: "memory");      \
    __builtin_amdgcn_sched_barrier(0);                               \
    __builtin_amdgcn_s_barrier();                                    \
    __builtin_amdgcn_sched_barrier(0);                               \
  }
#define WAITVL(N)                                                         \
  {                                                                       \
    __builtin_amdgcn_sched_barrier(0);                                    \
    asm volatile("s_waitcnt vmcnt(" #N ") lgkmcnt(0)" ::: "memory");      \
    __builtin_amdgcn_sched_barrier(0);                                    \
  }

// ============================================================
// prep: bf16 conversions + transposes + tiled layouts
// ============================================================
__global__ __launch_bounds__(256, 4) void prep_kernel(
    const float* __restrict__ feat, const float* __restrict__ Wq,
    const float* __restrict__ Wk, const float* __restrict__ Wv,
    const float* __restrict__ W2, char* __restrict__ ws) {
  int tid = blockIdx.x * 256 + threadIdx.x;
  if (tid < 524288) {  // Xb: 8-elem chunks
    int r = tid >> 5, co = (tid & 31) * 8;
    const float* src = feat + (size_t)r * 256 + co;
    short8 v;
#pragma unroll
    for (int i = 0; i < 8; ++i) v[i] = (short)f2bf(src[i]);
    unsigned short* Xb = (unsigned short*)(ws + XB_OFF);
    *(short8*)(Xb + (size_t)r * 256 + (co ^ ((r & 7) << 3))) = v;
  } else if (tid < 917504) {  // Wall[m][d] = W*[d][m] (scale folded into Wq)
    int t2 = tid - 524288;
    int m = t2 >> 8, d = t2 & 255;
    int wsel = m >> 9, mm = m & 511;
    const float* W = (wsel == 0) ? Wq : ((wsel == 1) ? Wk : Wv);
    float v = W[(size_t)d * 512 + mm];
    if (wsel == 0) v *= SCALE_Q;
    unsigned short* Wall = (unsigned short*)(ws + WALL_OFF);
    Wall[(size_t)m * 256 + (d ^ ((m & 7) << 3))] = f2bf(v);
  } else {  // W2t TILED [t 2][ck 8][r 128][128B], granules p = gt ^ (r&7)
    int t3 = tid - 917504;
    int d = t3 >> 9, c = t3 & 511;
    int r = d & 127;
    size_t addr = (size_t)((d >> 7) * 8 + (c >> 6)) * 16384 + (size_t)r * 128 +
                  (size_t)((((c >> 3) & 7) ^ (r & 7)) * 16) + (c & 7) * 2;
    *(unsigned short*)(ws + W2T_OFF + addr) = f2bf(W2[(size_t)c * 256 + d]);
  }
}

// ============================================================
// proj: [16384,256] @ [256, 512*3] -> Q/K (tiled swz), Vt (frag-order)
// 1536 blocks (XCD-chunked swizzle), 4 waves, 128x128 tile, BK=64 dbuf
// ============================================================
__global__ __launch_bounds__(256, 2) void proj_kernel(char* __restrict__ ws) {
  __shared__ char smem[65536];  // A dbuf 2x16KB @0, B dbuf 2x16KB @32768
  const int tid = threadIdx.x;
  const int l = tid & 63, w = tid >> 6;
  const int g = l >> 4, m16 = l & 15;
  const int orig = blockIdx.x;
  const int wgid = (orig & 7) * 192 + (orig >> 3);  // bijective (1536%8==0)
  const int nt = wgid % 12, mtb = wgid / 12;
  const char* XbT = ws + XB_OFF + (size_t)mtb * 65536;     // [128 r][512B]
  const char* WallT = ws + WALL_OFF + (size_t)nt * 65536;  // [128 r][512B]

  auto stage = [&](int buf, int kt) {
#pragma unroll
    for (int j = 0; j < 4; ++j) {
      int idx = j * 256 + tid;  // r=idx>>3, p=idx&7
      int r = idx >> 3, p = idx & 7;
      glds16(XbT + r * 512 + kt * 128 + p * 16, smem + buf * 16384 + idx * 16);
      glds16(WallT + r * 512 + kt * 128 + p * 16,
             smem + 32768 + buf * 16384 + idx * 16);
    }
  };

  const int mr = (w >> 1) * 64, nr = (w & 1) * 64;
  const int fxor = (m16 & 7) << 4;
  const f32x4 fz = {0.f, 0.f, 0.f, 0.f};
  f32x4 acc[4][4];
#pragma unroll
  for (int i = 0; i < 4; ++i)
#pragma unroll
    for (int j = 0; j < 4; ++j) acc[i][j] = fz;

  stage(0, 0);
  BAR_ALL();
#pragma unroll 1
  for (int kt = 0; kt < 4; ++kt) {
    if (kt < 3) stage((kt + 1) & 1, kt + 1);
    const char* Ab = smem + (kt & 1) * 16384;
    const char* Bb = smem + 32768 + (kt & 1) * 16384;
#pragma unroll
    for (int ks = 0; ks < 2; ++ks) {
      int off = (16 * g + 64 * ks) ^ fxor;
      short8 af[4], bf[4];
#pragma unroll
      for (int i = 0; i < 4; ++i)
        af[i] = *(const short8*)(Ab + (mr + i * 16 + m16) * 128 + off);
#pragma unroll
      for (int i = 0; i < 4; ++i)
        bf[i] = *(const short8*)(Bb + (nr + i * 16 + m16) * 128 + off);
#pragma unroll
      for (int mi = 0; mi < 4; ++mi)
#pragma unroll
        for (int ni = 0; ni < 4; ++ni)
          acc[mi][ni] = mfma16(af[mi], bf[ni], acc[mi][ni]);
    }
    BAR_ALL();
  }

  // ---- epilogue ----
  const int colg = nt * 128 + nr;
  const int tcat = colg >> 9;       // 0=Q 1=K 2=V
  const int cin_base = colg & 511;  // col within tensor
  char* wbuf = smem + w * 2048;     // per-wave [16][128B]
  if (tcat < 2) {
    char* dst = ws + (tcat == 0 ? Q_OFF : K_OFF) +
                ((size_t)(mtb * 8 + (cin_base >> 6))) * 16384;
#pragma unroll
    for (int mi = 0; mi < 4; ++mi) {
#pragma unroll
      for (int ni = 0; ni < 4; ++ni)
#pragma unroll
        for (int j = 0; j < 4; ++j) {
          int r = g * 4 + j, c = ni * 16 + m16;
          *(unsigned short*)(wbuf + r * 128 + ((2 * c) ^ ((r & 7) << 4))) =
              f2bf(acc[mi][ni][j]);
        }
      asm volatile("s_waitcnt lgkmcnt(0)" ::: "memory");
      __builtin_amdgcn_sched_barrier(0);
#pragma unroll
      for (int s = 0; s < 2; ++s) {
        int cid = l + 64 * s;
        int r2 = cid >> 3, gi = cid & 7;
        short8 v = *(const short8*)(wbuf + r2 * 128 + gi * 16);
        int rt = mr + mi * 16 + r2;  // row in tile
        *(short8*)(dst + (size_t)rt * 128 + gi * 16) = v;
      }
    }
  } else {
    // V: gather column l per mi; write FRAG-ORDER Vt granules
    int cin = cin_base + l;
    int grow0 = mtb * 128 + mr;
    int z2 = grow0 >> 11;
    int k0 = (grow0 & 2047) >> 5;
    char* vbase = ws + VT_OFF + (size_t)z2 * 2097152 +
                  (size_t)(cin >> 6) * 4096 + (size_t)((cin >> 4) & 3) * 1024 +
                  (size_t)(cin & 15) * 16;
#pragma unroll
    for (int mi = 0; mi < 4; ++mi) {
#pragma unroll
      for (int ni = 0; ni < 4; ++ni)
#pragma unroll
        for (int j = 0; j < 4; ++j) {
          int r = g * 4 + j, c = ni * 16 + m16;
          *(unsigned short*)(wbuf + r * 128 + ((2 * c) ^ ((r & 7) << 4))) =
              f2bf(acc[mi][ni][j]);
        }
      asm volatile("s_waitcnt lgkmcnt(0)" ::: "memory");
      __builtin_amdgcn_sched_barrier(0);
      unsigned short vals[16];
#pragma unroll
      for (int r2 = 0; r2 < 16; ++r2)
        vals[r2] = *(const unsigned short*)(wbuf + r2 * 128 +
                                            ((2 * l) ^ ((r2 & 7) << 4)));
      short8 v0, v1;
#pragma unroll
      for (int i2 = 0; i2 < 8; ++i2) {
        v0[i2] = (short)vals[i2];
        v1[i2] = (short)vals[8 + i2];
      }
      int kt32 = k0 + (mi >> 1);
      int gb = (mi & 1) * 2;
      *(short8*)(vbase + (size_t)kt32 * 32768 + gb * 256) = v0;
      *(short8*)(vbase + (size_t)kt32 * 32768 + (gb + 1) * 256) = v1;
    }
  }
}

// ============================================================
// qk: S(f16, FRAG-ORDER) = Q @ K^T; 128x128 tiles, K=512, BK=64 dbuf
// ============================================================
__global__ __launch_bounds__(256, 2) void qk_kernel(
    const char* __restrict__ ws, char* __restrict__ Sb, int nb, int b0) {
  __shared__ char smem[65536];  // A dbuf 2x16KB @0, B dbuf 2x16KB @32768
  const int tid = threadIdx.x;
  const int bid = blockIdx.x;
  const int z = bid % nb, tile = bid / nb;
  const int mt = tile >> 4, ntq = tile & 15;
  const int b = b0 + z;
  const int l = tid & 63, w = tid >> 6;
  const int g = l >> 4, m16 = l & 15;
  const int fxor = (m16 & 7) << 4;
  const char* Qt = ws + Q_OFF + (size_t)(b * 16 + mt) * 131072;
  const char* Kt = ws + K_OFF + (size_t)(b * 16 + ntq) * 131072;

  auto stage = [&](int buf, int kt) {
#pragma unroll
    for (int j = 0; j < 4; ++j) {
      int idx = j * 256 + tid;
      glds16(Qt + (size_t)kt * 16384 + idx * 16, smem + buf * 16384 + idx * 16);
      glds16(Kt + (size_t)kt * 16384 + idx * 16,
             smem + 32768 + buf * 16384 + idx * 16);
    }
  };

  const int mr = (w >> 1) * 64, nr = (w & 1) * 64;
  const f32x4 fz = {0.f, 0.f, 0.f, 0.f};
  f32x4 acc[4][4];
#pragma unroll
  for (int i = 0; i < 4; ++i)
#pragma unroll
    for (int j = 0; j < 4; ++j) acc[i][j] = fz;

  stage(0, 0);
  BAR_ALL();
#pragma unroll 1
  for (int kt = 0; kt < 8; ++kt) {
    if (kt < 7) stage((kt + 1) & 1, kt + 1);
    const char* Ab = smem + (kt & 1) * 16384;
    const char* Bb = smem + 32768 + (kt & 1) * 16384;
#pragma unroll
    for (int ks = 0; ks < 2; ++ks) {
      int off = (16 * g + 64 * ks) ^ fxor;
      short8 af[4], bf[4];
#pragma unroll
      for (int i = 0; i < 4; ++i)
        af[i] = *(const short8*)(Ab + (mr + i * 16 + m16) * 128 + off);
#pragma unroll
      for (int i = 0; i < 4; ++i)
        bf[i] = *(const short8*)(Bb + (nr + i * 16 + m16) * 128 + off);
#pragma unroll
      for (int mi = 0; mi < 4; ++mi)
#pragma unroll
        for (int ni = 0; ni < 4; ++ni)
          acc[mi][ni] = mfma16(af[mi], bf[ni], acc[mi][ni]);
    }
    BAR_ALL();
  }

  // ---- epilogue: f16 repack [128][272B] in LDS, frag-order linear stores --
#pragma unroll
  for (int mi = 0; mi < 4; ++mi)
#pragma unroll
    for (int ni = 0; ni < 4; ++ni)
#pragma unroll
      for (int j = 0; j < 4; ++j) {
        int r = mr + mi * 16 + g * 4 + j, c = nr + ni * 16 + m16;
        *(unsigned short*)(smem + r * 272 + 2 * c) =
            __builtin_bit_cast(unsigned short, (_Float16)acc[mi][ni][j]);
      }
  BAR_LGKM();
  char* Sz = Sb + (size_t)z * 8388608;
#pragma unroll
  for (int it = 0; it < 8; ++it) {
    int idx = it * 256 + tid;
    int rgh = idx >> 10, rem = idx & 1023;
    int kt32L = rem >> 8, rem2 = rem & 255;
    int mi2 = rem2 >> 6, lslot = rem2 & 63;
    int row = rgh * 64 + mi2 * 16 + (lslot & 15);
    int bcol = kt32L * 64 + (lslot >> 4) * 16;
    short8 v = *(const short8*)(smem + row * 272 + bcol);
    *(short8*)(Sz + (size_t)(mt * 2 + rgh) * 262144 +
               (size_t)(ntq * 4 + kt32L) * 4096 + mi2 * 1024 + lslot * 16) = v;
  }
}

// ============================================================
// stats: fixed-max softmax transform, in place. Block = (z, rg, mi):
// 16 rows, one contiguous 64KB mi-slice. 128*nb blocks.
// P_unnorm = exp2(s-12) bf16; rs[row] = 1/sum -> RS table.
// ============================================================
__global__ __launch_bounds__(256, 4) void stats_kernel(
    char* __restrict__ Sb, float* __restrict__ rs_out, int nb, int b0) {
  const int tid = threadIdx.x;
  const int bid = blockIdx.x;
  const int z = bid % nb, rem = bid / nb;
  const int rg = rem >> 2, mi = rem & 3;
  char* Base = Sb + (size_t)z * 8388608 + (size_t)rg * 262144 + mi * 1024;
  float sum = 0.f;
#pragma unroll 4
  for (int i = 0; i < 16; ++i) {
    int idx = i * 256 + tid;
    int kt32 = idx >> 6, l2 = idx & 63;
    char* p = Base + (size_t)kt32 * 4096 + l2 * 16;
    h8 hv = *(const h8*)p;
    short8 pk;
#pragma unroll
    for (int j = 0; j < 8; ++j) {
      float e = exp2f((float)hv[j] - FIXMAX);
      sum += e;
      pk[j] = (short)f2bf(e);
    }
    *(short8*)p = pk;
  }
  sum += __shfl_xor(sum, 16);
  sum += __shfl_xor(sum, 32);
  __shared__ float red[4][16];
  const int w = tid >> 6, l = tid & 63;
  if (l < 16) red[w][l] = sum;
  __syncthreads();
  if (tid < 16) {
    float s = red[0][tid] + red[1][tid] + red[2][tid] + red[3][tid];
    rs_out[(size_t)(b0 + z) * 2048 + rg * 64 + mi * 16 + tid] = 1.0f / s;
  }
}

// ============================================================
// pv: O = P_unnorm @ V, rs-normalized epilogue, O -> ws (tiled)
// block = 64 rows x 512 cols; 512 thr, 8 waves (wave w: cols w*64..+64)
// BK=64, 32 kt, ONE barrier/kt. P direct global->regs (frag-order,
// L1-broadcast across waves, dbuf pA/pB); V glds frag-order dbuf 2x64KB.
// Counted wait: vmcnt(16) = exactly the next-kt's 8 P-loads + 8 V-glds.
// ============================================================
__global__ __launch_bounds__(512, 2) void pv_kernel(
    char* __restrict__ ws, char* __restrict__ Sb, int nb, int b0) {
  __shared__ char smem[131072];  // V dbuf 2x64KB; epilogue wbuf overlays
  const int tid = threadIdx.x;
  const int bid = blockIdx.x;
  const int z = bid % nb, mt64 = bid / nb;  // mt64: 0..31
  const int b = b0 + z;
  const int l = tid & 63, w = tid >> 6;
  const int g = l >> 4, m16 = l & 15;
  const char* Pr = Sb + (size_t)z * 8388608 + (size_t)mt64 * 262144;
  const char* Vt = ws + VT_OFF + (size_t)b * 2097152;

  const f32x4 fz = {0.f, 0.f, 0.f, 0.f};
  f32x4 acc[4][4];
#pragma unroll
  for (int i = 0; i < 4; ++i)
#pragma unroll
    for (int j = 0; j < 4; ++j) acc[i][j] = fz;

  auto loadP = [&](short8(&pf)[8], int kt) {  // kt in BK64 units
    const char* p = Pr + (size_t)kt * 8192 + l * 16;
#pragma unroll
    for (int s = 0; s < 2; ++s)
#pragma unroll
      for (int mi = 0; mi < 4; ++mi)
        pf[s * 4 + mi] = *(const short8*)(p + s * 4096 + mi * 1024);
  };
  auto stageV = [&](int buf, int kt) {  // 64KB, 8 glds/thread
#pragma unroll
    for (int j = 0; j < 8; ++j) {
      int idx = j * 512 + tid;
      glds16(Vt + (size_t)kt * 65536 + idx * 16,
             smem + buf * 65536 + idx * 16);
    }
  };
  auto compute = [&](int buf, short8(&pf)[8]) {
    const char* Vb = smem + buf * 65536 + w * 4096 + l * 16;
#pragma unroll
    for (int s = 0; s < 2; ++s) {
      short8 vf[4];
#pragma unroll
      for (int ni = 0; ni < 4; ++ni)
        vf[ni] = *(const short8*)(Vb + s * 32768 + ni * 1024);
#pragma unroll
      for (int mi = 0; mi < 4; ++mi)
#pragma unroll
        for (int ni = 0; ni < 4; ++ni)
          acc[mi][ni] = mfma16(pf[s * 4 + mi], vf[ni], acc[mi][ni]);
    }
  };

  short8 pA[8], pB[8];
  loadP(pA, 0);
  stageV(0, 0);
  WAITVL(0);
  BAR_SYNC();
#pragma unroll 1
  for (int kt2 = 0; kt2 < 16; ++kt2) {
    const int kt = kt2 * 2;
    // half A: compute kt from buf0/pA; prefetch kt+1 into buf1/pB
    if (kt + 1 < 32) {
      loadP(pB, kt + 1);
      stageV(1, kt + 1);
      WAITVL(16);
    } else {
      WAITVL(0);
    }
    BAR_SYNC();
    compute(0, pA);
    // half B: compute kt+1 from buf1/pB; prefetch kt+2 into buf0/pA
    if (kt + 2 < 32) {
      loadP(pA, kt + 2);
      stageV(0, kt + 2);
      WAITVL(16);
    } else {
      WAITVL(0);
    }
    BAR_SYNC();
    compute(1, pB);
  }
  BAR_ALL();  // all LDS reads retired before epilogue reuses smem

  // ---- rs-normalize, then store O (bf16, Q-style tiled) ----
  const float* rsp = (const float*)(ws + RS_OFF) + (size_t)b * 2048 + mt64 * 64;
#pragma unroll
  for (int mi = 0; mi < 4; ++mi) {
    f32x4 rv;
#pragma unroll
    for (int j = 0; j < 4; ++j) rv[j] = rsp[mi * 16 + g * 4 + j];
#pragma unroll
    for (int ni = 0; ni < 4; ++ni) acc[mi][ni] *= rv;
  }
  char* wbuf = smem + w * 2048;  // per-wave [16][128B]
  char* dst = ws + O_OFF + ((size_t)(b * 16 + (mt64 >> 1)) * 8 + w) * 16384 +
              (size_t)(mt64 & 1) * 8192;
#pragma unroll 1
  for (int mi = 0; mi < 4; ++mi) {
#pragma unroll
    for (int ni = 0; ni < 4; ++ni)
#pragma unroll
      for (int j = 0; j < 4; ++j) {
        int r = g * 4 + j, c = ni * 16 + m16;
        *(unsigned short*)(wbuf + r * 128 + ((2 * c) ^ ((r & 7) << 4))) =
            f2bf(acc[mi][ni][j]);
      }
    asm volatile("s_waitcnt lgkmcnt(0)" ::: "memory");
    __builtin_amdgcn_sched_barrier(0);
#pragma unroll
    for (int s = 0; s < 2; ++s) {
      int cid = l + 64 * s;
      int r2 = cid >> 3, gi = cid & 7;
      short8 v = *(const short8*)(wbuf + r2 * 128 + gi * 16);
      *(short8*)(dst + (size_t)(mi * 16 + r2) * 128 + gi * 16) = v;
    }
  }
}

// ============================================================
// fc2: out = lrelu(O @ W2 + b2) + feat ; qk-clone structure
// grid 256: mtF = bid>>1 (128 row-tiles), ntF = bid&1 (2 col-tiles)
// ============================================================
__global__ __launch_bounds__(256, 2) void fc2_kernel(
    const char* __restrict__ ws, const float* __restrict__ feat,
    const float* __restrict__ b2, float* __restrict__ out) {
  __shared__ char smem[65536];  // A dbuf 2x16KB @0, B dbuf 2x16KB @32768
  const int tid = threadIdx.x;
  const int mtF = blockIdx.x >> 1, ntF = blockIdx.x & 1;
  const int l = tid & 63, w = tid >> 6;
  const int g = l >> 4, m16 = l & 15;
  const int fxor = (m16 & 7) << 4;
  const char* At = ws + O_OFF + (size_t)mtF * 131072;
  const char* Bt = ws + W2T_OFF + (size_t)ntF * 131072;

  auto stage = [&](int buf, int kt) {
#pragma unroll
    for (int j = 0; j < 4; ++j) {
      int idx = j * 256 + tid;
      glds16(At + (size_t)kt * 16384 + idx * 16, smem + buf * 16384 + idx * 16);
      glds16(Bt + (size_t)kt * 16384 + idx * 16,
             smem + 32768 + buf * 16384 + idx * 16);
    }
  };

  const int mr = (w >> 1) * 64, nr = (w & 1) * 64;
  const f32x4 fz = {0.f, 0.f, 0.f, 0.f};
  f32x4 acc[4][4];
#pragma unroll
  for (int i = 0; i < 4; ++i)
#pragma unroll
    for (int j = 0; j < 4; ++j) acc[i][j] = fz;

  stage(0, 0);
  BAR_ALL();
#pragma unroll 1
  for (int kt = 0; kt < 8; ++kt) {
    if (kt < 7) stage((kt + 1) & 1, kt + 1);
    const char* Ab = smem + (kt & 1) * 16384;
    const char* Bb = smem + 32768 + (kt & 1) * 16384;
#pragma unroll
    for (int ks = 0; ks < 2; ++ks) {
      int off = (16 * g + 64 * ks) ^ fxor;
      short8 af[4], bf[4];
#pragma unroll
      for (int i = 0; i < 4; ++i)
        af[i] = *(const short8*)(Ab + (mr + i * 16 + m16) * 128 + off);
#pragma unroll
      for (int i = 0; i < 4; ++i)
        bf[i] = *(const short8*)(Bb + (nr + i * 16 + m16) * 128 + off);
#pragma unroll
      for (int mi = 0; mi < 4; ++mi)
#pragma unroll
        for (int ni = 0; ni < 4; ++ni)
          acc[mi][ni] = mfma16(af[mi], bf[ni], acc[mi][ni]);
    }
    BAR_ALL();
  }

  // ---- epilogue: bias + leakyrelu + residual, f32 stores ----
#pragma unroll
  for (int mi = 0; mi < 4; ++mi)
#pragma unroll
    for (int ni = 0; ni < 4; ++ni) {
      int d = ntF * 128 + nr + ni * 16 + m16;
      float bias = b2[d];
#pragma unroll
      for (int j = 0; j < 4; ++j) {
        size_t m = (size_t)mtF * 128 + mr + mi * 16 + g * 4 + j;
        float v = acc[mi][ni][j] + bias;
        v = v > 0.f ? v : 0.2f * v;
        out[m * 256 + d] = v + feat[m * 256 + d];
      }
    }
}

// ============================================================
extern "C" void kernel_launch(void* const* d_in, const int* in_sizes, int n_in,
                              void* d_out, int out_size, void* d_ws, size_t ws_size,
                              hipStream_t stream) {
  const float* feat = (const float*)d_in[0];
  const float* Wq = (const float*)d_in[1];
  const float* Wk = (const float*)d_in[2];
  const float* Wv = (const float*)d_in[3];
  const float* W2 = (const float*)d_in[4];
  const float* b2 = (const float*)d_in[5];
  float* out = (float*)d_out;
  char* ws = (char*)d_ws;
  (void)in_sizes; (void)n_in; (void)out_size;

  prep_kernel<<<4096, 256, 0, stream>>>(feat, Wq, Wk, Wv, W2, ws);
  proj_kernel<<<1536, 256, 0, stream>>>(ws);

  const size_t per_batch = 8388608ul;  // S/P: 2048 rows * 4096 B
  int nb = 8;
  while (nb > 1 && S_OFF + (size_t)nb * per_batch > ws_size) nb >>= 1;
  char* Sb = ws + S_OFF;
  float* rs = (float*)(ws + RS_OFF);
  for (int b0 = 0; b0 < 8; b0 += nb) {
    qk_kernel<<<256 * nb, 256, 0, stream>>>(ws, Sb, nb, b0);
    stats_kernel<<<128 * nb, 256, 0, stream>>>(Sb, rs, nb, b0);
    pv_kernel<<<32 * nb, 512, 0, stream>>>(ws, Sb, nb, b0);
  }
  fc2_kernel<<<256, 256, 0, stream>>>(ws, feat, b2, out);
}

// Round 13
// 171.836 us; speedup vs baseline: 1.2739x; 1.0302x over previous
//
#include <hip/hip_runtime.h>
#include <cstdint>

// ---------------- problem constants ----------------
// features [8,2048,256] f32; Wq/Wk/Wv [256,512]; W2 [512,256]; b2 [256]
// out [8,2048,256] f32
#define NBATCH 8
#define NSEQ   2048
#define NROWS  16384

typedef __attribute__((ext_vector_type(4))) float  f32x4;
typedef __attribute__((ext_vector_type(8))) short  short8;
typedef __attribute__((ext_vector_type(8))) __bf16 bf16x8;
typedef __attribute__((ext_vector_type(8))) _Float16 h8;

// ---------------- workspace layout (bytes) ----------------
// Xb/Wall: row-granule-swizzled bf16 (granule ^= row&7) -- glds-staged
// Q/K : TILED [t 128][ck 8][r 128][128B], granules stored[p]=true[p^(r&7)]
// Vt  : FRAG-ORDER [b][kt32 64][w' 8][ni 4][lane 64][16B]
// W2t : TILED like Q/K: [t 2][ck 8][r 128][128B], granules p^(r&7)
// O   : TILED like Q/K: [t 128][ck 8][r 128][128B], granules p^(r&7)
// RS  : [b 8][2048] f32  (1/softmax-denominator per row)
// S/P : FRAG-ORDER per batch-slot z: [rg 32][kt32 64][mi 4][lane 64][16B]
//       qk writes f16 S; stats overwrites in place with bf16 exp2(s-12)
#define XB_OFF   0ul          // 8388608
#define WALL_OFF 8388608ul    // 786432 (Wq^T*scale | Wk^T | Wv^T)
#define Q_OFF    9175040ul    // 16777216 (pre-scaled by log2e/sqrt(512))
#define K_OFF    25952256ul   // 16777216
#define VT_OFF   42729472ul   // 16777216
#define W2T_OFF  59506688ul   // 262144
#define O_OFF    59768832ul   // 16777216
#define RS_OFF   76546048ul   // 65536
#define S_OFF    76611584ul   // nb * 8388608

#define SCALE_Q 0.063758746f  // (1/sqrt(512)) * log2(e)
#define FIXMAX  12.0f         // fixed softmax max (log2 domain); rs renormalizes

__device__ __forceinline__ unsigned short f2bf(float f) {
  unsigned u = __builtin_bit_cast(unsigned, f);
  return (unsigned short)((u + 0x7fffu + ((u >> 16) & 1u)) >> 16);  // RNE
}

__device__ __forceinline__ f32x4 mfma16(short8 a, short8 b, f32x4 c) {
  return __builtin_amdgcn_mfma_f32_16x16x32_bf16(
      __builtin_bit_cast(bf16x8, a), __builtin_bit_cast(bf16x8, b), c, 0, 0, 0);
}

__device__ __forceinline__ void glds16(const void* g, void* l) {
  __builtin_amdgcn_global_load_lds(
      (const __attribute__((address_space(1))) void*)g,
      (__attribute__((address_space(3))) void*)l, 16, 0, 0);
}

#define BAR_SYNC()                     \
  {                                    \
    __builtin_amdgcn_sched_barrier(0); \
    __builtin_amdgcn_s_barrier();      \
    __builtin_amdgcn_sched_barrier(0); \
  }
#define BAR_LGKM()                                           \
  {                                                          \
    asm volatile("s_waitcnt lgkmcnt(0)" ::: "memory");       \
    __builtin_amdgcn_sched_barrier(0);                       \
    __builtin_amdgcn_s_barrier();                            \
    __builtin_amdgcn_sched_barrier(0);                       \
  }
#define BAR_ALL()                                                    \
  {                                                                  \
    asm volatile("s_waitcnt vmcnt(0) lgkmcnt(0)" ::: "memory");      \
    __builtin_amdgcn_sched_barrier(0);                               \
    __builtin_amdgcn_s_barrier();                                    \
    __builtin_amdgcn_sched_barrier(0);                               \
  }
#define WAITVL(N)                                                         \
  {                                                                       \
    __builtin_amdgcn_sched_barrier(0);                                    \
    asm volatile("s_waitcnt vmcnt(" #N ") lgkmcnt(0)" ::: "memory");      \
    __builtin_amdgcn_sched_barrier(0);                                    \
  }

// ============================================================
// prep: bf16 conversions + transposes + tiled layouts
// ============================================================
__global__ __launch_bounds__(256, 4) void prep_kernel(
    const float* __restrict__ feat, const float* __restrict__ Wq,
    const float* __restrict__ Wk, const float* __restrict__ Wv,
    const float* __restrict__ W2, char* __restrict__ ws) {
  int tid = blockIdx.x * 256 + threadIdx.x;
  if (tid < 524288) {  // Xb: 8-elem chunks
    int r = tid >> 5, co = (tid & 31) * 8;
    const float* src = feat + (size_t)r * 256 + co;
    short8 v;
#pragma unroll
    for (int i = 0; i < 8; ++i) v[i] = (short)f2bf(src[i]);
    unsigned short* Xb = (unsigned short*)(ws + XB_OFF);
    *(short8*)(Xb + (size_t)r * 256 + (co ^ ((r & 7) << 3))) = v;
  } else if (tid < 917504) {  // Wall[m][d] = W*[d][m] (scale folded into Wq)
    int t2 = tid - 524288;
    int m = t2 >> 8, d = t2 & 255;
    int wsel = m >> 9, mm = m & 511;
    const float* W = (wsel == 0) ? Wq : ((wsel == 1) ? Wk : Wv);
    float v = W[(size_t)d * 512 + mm];
    if (wsel == 0) v *= SCALE_Q;
    unsigned short* Wall = (unsigned short*)(ws + WALL_OFF);
    Wall[(size_t)m * 256 + (d ^ ((m & 7) << 3))] = f2bf(v);
  } else {  // W2t TILED [t 2][ck 8][r 128][128B], granules p = gt ^ (r&7)
    int t3 = tid - 917504;
    int d = t3 >> 9, c = t3 & 511;
    int r = d & 127;
    size_t addr = (size_t)((d >> 7) * 8 + (c >> 6)) * 16384 + (size_t)r * 128 +
                  (size_t)((((c >> 3) & 7) ^ (r & 7)) * 16) + (c & 7) * 2;
    *(unsigned short*)(ws + W2T_OFF + addr) = f2bf(W2[(size_t)c * 256 + d]);
  }
}

// ============================================================
// proj: [16384,256] @ [256, 512*3] -> Q/K (tiled swz), Vt (frag-order)
// 1536 blocks (XCD-chunked swizzle), 4 waves, 128x128 tile, BK=64 dbuf
// ============================================================
__global__ __launch_bounds__(256, 2) void proj_kernel(char* __restrict__ ws) {
  __shared__ char smem[65536];  // A dbuf 2x16KB @0, B dbuf 2x16KB @32768
  const int tid = threadIdx.x;
  const int l = tid & 63, w = tid >> 6;
  const int g = l >> 4, m16 = l & 15;
  const int orig = blockIdx.x;
  const int wgid = (orig & 7) * 192 + (orig >> 3);  // bijective (1536%8==0)
  const int nt = wgid % 12, mtb = wgid / 12;
  const char* XbT = ws + XB_OFF + (size_t)mtb * 65536;     // [128 r][512B]
  const char* WallT = ws + WALL_OFF + (size_t)nt * 65536;  // [128 r][512B]

  auto stage = [&](int buf, int kt) {
#pragma unroll
    for (int j = 0; j < 4; ++j) {
      int idx = j * 256 + tid;  // r=idx>>3, p=idx&7
      int r = idx >> 3, p = idx & 7;
      glds16(XbT + r * 512 + kt * 128 + p * 16, smem + buf * 16384 + idx * 16);
      glds16(WallT + r * 512 + kt * 128 + p * 16,
             smem + 32768 + buf * 16384 + idx * 16);
    }
  };

  const int mr = (w >> 1) * 64, nr = (w & 1) * 64;
  const int fxor = (m16 & 7) << 4;
  const f32x4 fz = {0.f, 0.f, 0.f, 0.f};
  f32x4 acc[4][4];
#pragma unroll
  for (int i = 0; i < 4; ++i)
#pragma unroll
    for (int j = 0; j < 4; ++j) acc[i][j] = fz;

  stage(0, 0);
  BAR_ALL();
#pragma unroll 1
  for (int kt = 0; kt < 4; ++kt) {
    if (kt < 3) stage((kt + 1) & 1, kt + 1);
    const char* Ab = smem + (kt & 1) * 16384;
    const char* Bb = smem + 32768 + (kt & 1) * 16384;
#pragma unroll
    for (int ks = 0; ks < 2; ++ks) {
      int off = (16 * g + 64 * ks) ^ fxor;
      short8 af[4], bf[4];
#pragma unroll
      for (int i = 0; i < 4; ++i)
        af[i] = *(const short8*)(Ab + (mr + i * 16 + m16) * 128 + off);
#pragma unroll
      for (int i = 0; i < 4; ++i)
        bf[i] = *(const short8*)(Bb + (nr + i * 16 + m16) * 128 + off);
#pragma unroll
      for (int mi = 0; mi < 4; ++mi)
#pragma unroll
        for (int ni = 0; ni < 4; ++ni)
          acc[mi][ni] = mfma16(af[mi], bf[ni], acc[mi][ni]);
    }
    BAR_ALL();
  }

  // ---- epilogue ----
  const int colg = nt * 128 + nr;
  const int tcat = colg >> 9;       // 0=Q 1=K 2=V
  const int cin_base = colg & 511;  // col within tensor
  char* wbuf = smem + w * 2048;     // per-wave [16][128B]
  if (tcat < 2) {
    char* dst = ws + (tcat == 0 ? Q_OFF : K_OFF) +
                ((size_t)(mtb * 8 + (cin_base >> 6))) * 16384;
#pragma unroll
    for (int mi = 0; mi < 4; ++mi) {
#pragma unroll
      for (int ni = 0; ni < 4; ++ni)
#pragma unroll
        for (int j = 0; j < 4; ++j) {
          int r = g * 4 + j, c = ni * 16 + m16;
          *(unsigned short*)(wbuf + r * 128 + ((2 * c) ^ ((r & 7) << 4))) =
              f2bf(acc[mi][ni][j]);
        }
      asm volatile("s_waitcnt lgkmcnt(0)" ::: "memory");
      __builtin_amdgcn_sched_barrier(0);
#pragma unroll
      for (int s = 0; s < 2; ++s) {
        int cid = l + 64 * s;
        int r2 = cid >> 3, gi = cid & 7;
        short8 v = *(const short8*)(wbuf + r2 * 128 + gi * 16);
        int rt = mr + mi * 16 + r2;  // row in tile
        *(short8*)(dst + (size_t)rt * 128 + gi * 16) = v;
      }
    }
  } else {
    // V: gather column l per mi; write FRAG-ORDER Vt granules
    int cin = cin_base + l;
    int grow0 = mtb * 128 + mr;
    int z2 = grow0 >> 11;
    int k0 = (grow0 & 2047) >> 5;
    char* vbase = ws + VT_OFF + (size_t)z2 * 2097152 +
                  (size_t)(cin >> 6) * 4096 + (size_t)((cin >> 4) & 3) * 1024 +
                  (size_t)(cin & 15) * 16;
#pragma unroll
    for (int mi = 0; mi < 4; ++mi) {
#pragma unroll
      for (int ni = 0; ni < 4; ++ni)
#pragma unroll
        for (int j = 0; j < 4; ++j) {
          int r = g * 4 + j, c = ni * 16 + m16;
          *(unsigned short*)(wbuf + r * 128 + ((2 * c) ^ ((r & 7) << 4))) =
              f2bf(acc[mi][ni][j]);
        }
      asm volatile("s_waitcnt lgkmcnt(0)" ::: "memory");
      __builtin_amdgcn_sched_barrier(0);
      unsigned short vals[16];
#pragma unroll
      for (int r2 = 0; r2 < 16; ++r2)
        vals[r2] = *(const unsigned short*)(wbuf + r2 * 128 +
                                            ((2 * l) ^ ((r2 & 7) << 4)));
      short8 v0, v1;
#pragma unroll
      for (int i2 = 0; i2 < 8; ++i2) {
        v0[i2] = (short)vals[i2];
        v1[i2] = (short)vals[8 + i2];
      }
      int kt32 = k0 + (mi >> 1);
      int gb = (mi & 1) * 2;
      *(short8*)(vbase + (size_t)kt32 * 32768 + gb * 256) = v0;
      *(short8*)(vbase + (size_t)kt32 * 32768 + (gb + 1) * 256) = v1;
    }
  }
}

// ============================================================
// qk: S(f16, FRAG-ORDER) = Q @ K^T; 128x128 tiles, K=512, BK=64 dbuf
// counted WAITVL(8): staged kt+1 stays in flight across compute(kt)
// ============================================================
__global__ __launch_bounds__(256, 2) void qk_kernel(
    const char* __restrict__ ws, char* __restrict__ Sb, int nb, int b0) {
  __shared__ char smem[65536];  // A dbuf 2x16KB @0, B dbuf 2x16KB @32768
  const int tid = threadIdx.x;
  const int bid = blockIdx.x;
  const int z = bid % nb, tile = bid / nb;
  const int mt = tile >> 4, ntq = tile & 15;
  const int b = b0 + z;
  const int l = tid & 63, w = tid >> 6;
  const int g = l >> 4, m16 = l & 15;
  const int fxor = (m16 & 7) << 4;
  const char* Qt = ws + Q_OFF + (size_t)(b * 16 + mt) * 131072;
  const char* Kt = ws + K_OFF + (size_t)(b * 16 + ntq) * 131072;

  auto stage = [&](int buf, int kt) {
#pragma unroll
    for (int j = 0; j < 4; ++j) {
      int idx = j * 256 + tid;
      glds16(Qt + (size_t)kt * 16384 + idx * 16, smem + buf * 16384 + idx * 16);
      glds16(Kt + (size_t)kt * 16384 + idx * 16,
             smem + 32768 + buf * 16384 + idx * 16);
    }
  };

  const int mr = (w >> 1) * 64, nr = (w & 1) * 64;
  const f32x4 fz = {0.f, 0.f, 0.f, 0.f};
  f32x4 acc[4][4];
#pragma unroll
  for (int i = 0; i < 4; ++i)
#pragma unroll
    for (int j = 0; j < 4; ++j) acc[i][j] = fz;

  stage(0, 0);
#pragma unroll 1
  for (int kt = 0; kt < 8; ++kt) {
    if (kt < 7) {
      stage((kt + 1) & 1, kt + 1);
      WAITVL(8);  // drain kt's stage only; kt+1 stays in flight
    } else {
      WAITVL(0);
    }
    BAR_SYNC();
    const char* Ab = smem + (kt & 1) * 16384;
    const char* Bb = smem + 32768 + (kt & 1) * 16384;
#pragma unroll
    for (int ks = 0; ks < 2; ++ks) {
      int off = (16 * g + 64 * ks) ^ fxor;
      short8 af[4], bf[4];
#pragma unroll
      for (int i = 0; i < 4; ++i)
        af[i] = *(const short8*)(Ab + (mr + i * 16 + m16) * 128 + off);
#pragma unroll
      for (int i = 0; i < 4; ++i)
        bf[i] = *(const short8*)(Bb + (nr + i * 16 + m16) * 128 + off);
#pragma unroll
      for (int mi = 0; mi < 4; ++mi)
#pragma unroll
        for (int ni = 0; ni < 4; ++ni)
          acc[mi][ni] = mfma16(af[mi], bf[ni], acc[mi][ni]);
    }
    BAR_LGKM();  // reads of this buf retired before next stage overwrites
  }

  // ---- epilogue: f16 repack [128][272B] in LDS, frag-order linear stores --
#pragma unroll
  for (int mi = 0; mi < 4; ++mi)
#pragma unroll
    for (int ni = 0; ni < 4; ++ni)
#pragma unroll
      for (int j = 0; j < 4; ++j) {
        int r = mr + mi * 16 + g * 4 + j, c = nr + ni * 16 + m16;
        *(unsigned short*)(smem + r * 272 + 2 * c) =
            __builtin_bit_cast(unsigned short, (_Float16)acc[mi][ni][j]);
      }
  BAR_LGKM();
  char* Sz = Sb + (size_t)z * 8388608;
#pragma unroll
  for (int it = 0; it < 8; ++it) {
    int idx = it * 256 + tid;
    int rgh = idx >> 10, rem = idx & 1023;
    int kt32L = rem >> 8, rem2 = rem & 255;
    int mi2 = rem2 >> 6, lslot = rem2 & 63;
    int row = rgh * 64 + mi2 * 16 + (lslot & 15);
    int bcol = kt32L * 64 + (lslot >> 4) * 16;
    short8 v = *(const short8*)(smem + row * 272 + bcol);
    *(short8*)(Sz + (size_t)(mt * 2 + rgh) * 262144 +
               (size_t)(ntq * 4 + kt32L) * 4096 + mi2 * 1024 + lslot * 16) = v;
  }
}

// ============================================================
// stats: fixed-max softmax transform, in place. Block = (z, rg, mi):
// 16 rows, one contiguous 64KB mi-slice. 128*nb blocks.
// ============================================================
__global__ __launch_bounds__(256, 4) void stats_kernel(
    char* __restrict__ Sb, float* __restrict__ rs_out, int nb, int b0) {
  const int tid = threadIdx.x;
  const int bid = blockIdx.x;
  const int z = bid % nb, rem = bid / nb;
  const int rg = rem >> 2, mi = rem & 3;
  char* Base = Sb + (size_t)z * 8388608 + (size_t)rg * 262144 + mi * 1024;
  float sum = 0.f;
#pragma unroll 4
  for (int i = 0; i < 16; ++i) {
    int idx = i * 256 + tid;
    int kt32 = idx >> 6, l2 = idx & 63;
    char* p = Base + (size_t)kt32 * 4096 + l2 * 16;
    h8 hv = *(const h8*)p;
    short8 pk;
#pragma unroll
    for (int j = 0; j < 8; ++j) {
      float e = exp2f((float)hv[j] - FIXMAX);
      sum += e;
      pk[j] = (short)f2bf(e);
    }
    *(short8*)p = pk;
  }
  sum += __shfl_xor(sum, 16);
  sum += __shfl_xor(sum, 32);
  __shared__ float red[4][16];
  const int w = tid >> 6, l = tid & 63;
  if (l < 16) red[w][l] = sum;
  __syncthreads();
  if (tid < 16) {
    float s = red[0][tid] + red[1][tid] + red[2][tid] + red[3][tid];
    rs_out[(size_t)(b0 + z) * 2048 + rg * 64 + mi * 16 + tid] = 1.0f / s;
  }
}

// ============================================================
// pv: O = P_unnorm @ V, rs-normalized epilogue, O -> ws (tiled)
// block = 64 rows x 256 cols (cb half); 256 thr, 4 waves (wave: 64 cols)
// grid 64*nb = 512 -> 2 blocks/CU. BK=32, 64 kt.
// DEPTH-2 pipeline: V 3-buffer ring staged 2 ahead; P triple-buffered in
// NAMED regs pA/pB/pC (loop hand-grouped x3 so all idx compile-time).
// Steady WAITVL(16) leaves kt+1,kt+2 in flight (2 compute phases of hiding).
// Safety: buf[kt%3] overwritten at iter kt+1's stage, which follows iter
// kt's trailing barrier (all reads retired).
// ============================================================
__global__ __launch_bounds__(256, 2) void pv_kernel(
    char* __restrict__ ws, char* __restrict__ Sb, int nb, int b0) {
  __shared__ char smem[49152];  // V ring 3x16KB; epilogue wbuf overlays
  const int tid = threadIdx.x;
  const int bid = blockIdx.x;
  const int z = bid % nb, tile = bid / nb;
  const int cb = tile & 1, mt64 = tile >> 1;  // cb: col half, mt64: row block
  const int b = b0 + z;
  const int l = tid & 63, w = tid >> 6;
  const int g = l >> 4, m16 = l & 15;
  const char* Pr = Sb + (size_t)z * 8388608 + (size_t)mt64 * 262144;
  const char* Vt = ws + VT_OFF + (size_t)b * 2097152 + (size_t)cb * 16384;

  const f32x4 fz = {0.f, 0.f, 0.f, 0.f};
  f32x4 acc[4][4];
#pragma unroll
  for (int i = 0; i < 4; ++i)
#pragma unroll
    for (int j = 0; j < 4; ++j) acc[i][j] = fz;

  auto loadP = [&](short8(&pf)[4], int kt) {  // frag-order, coalesced 1KB/wave
    const char* p = Pr + (size_t)kt * 4096 + l * 16;
#pragma unroll
    for (int mi = 0; mi < 4; ++mi) pf[mi] = *(const short8*)(p + mi * 1024);
  };
  auto stageV = [&](int buf, int kt) {  // 16KB linear, 4 glds/thread
#pragma unroll
    for (int j = 0; j < 4; ++j) {
      int idx = j * 256 + tid;
      glds16(Vt + (size_t)kt * 32768 + idx * 16, smem + buf * 16384 + idx * 16);
    }
  };
  auto compute = [&](int buf, short8(&pf)[4]) {
    const char* Vb = smem + buf * 16384 + w * 4096 + l * 16;
    short8 vf[4];
#pragma unroll
    for (int ni = 0; ni < 4; ++ni) vf[ni] = *(const short8*)(Vb + ni * 1024);
#pragma unroll
    for (int mi = 0; mi < 4; ++mi)
#pragma unroll
      for (int ni = 0; ni < 4; ++ni)
        acc[mi][ni] = mfma16(pf[mi], vf[ni], acc[mi][ni]);
  };

  short8 pA[4], pB[4], pC[4];
  // prologue: issue kt=0 (phase A, buf0) and kt=1 (phase B, buf1)
  loadP(pA, 0);
  stageV(0, 0);
  loadP(pB, 1);
  stageV(1, 1);

#define PV_ITER(KT, PUSE, PDST, BUFC, BUFD)            \
  {                                                    \
    const int kt_ = (KT);                              \
    if (kt_ + 2 < 64) {                                \
      loadP(PDST, kt_ + 2);                            \
      stageV(BUFD, kt_ + 2);                           \
    }                                                  \
    if (kt_ < 62) {                                    \
      WAITVL(16);                                      \
    } else if (kt_ == 62) {                            \
      WAITVL(8);                                       \
    } else {                                           \
      WAITVL(0);                                       \
    }                                                  \
    BAR_SYNC();                                        \
    compute(BUFC, PUSE);                               \
    BAR_SYNC();                                        \
  }

#pragma unroll 1
  for (int gr = 0; gr < 21; ++gr) {  // kt = 3g, 3g+1, 3g+2 (0..62)
    const int k0 = gr * 3;
    PV_ITER(k0, pA, pC, 0, 2);
    PV_ITER(k0 + 1, pB, pA, 1, 0);
    PV_ITER(k0 + 2, pC, pB, 2, 1);
  }
  PV_ITER(63, pA, pC, 0, 2);  // 63%3==0 -> phase A
#undef PV_ITER

  // ---- rs-normalize, then store O (bf16, Q-style tiled) ----
  const float* rsp = (const float*)(ws + RS_OFF) + (size_t)b * 2048 + mt64 * 64;
#pragma unroll
  for (int mi = 0; mi < 4; ++mi) {
    f32x4 rv;
#pragma unroll
    for (int j = 0; j < 4; ++j) rv[j] = rsp[mi * 16 + g * 4 + j];
#pragma unroll
    for (int ni = 0; ni < 4; ++ni) acc[mi][ni] *= rv;
  }
  char* wbuf = smem + w * 2048;  // per-wave [16][128B]
  const int tI = b * 16 + (mt64 >> 1);
  char* dst = ws + O_OFF + ((size_t)tI * 8 + cb * 4 + w) * 16384 +
              (size_t)(mt64 & 1) * 8192;
#pragma unroll 1
  for (int mi = 0; mi < 4; ++mi) {
#pragma unroll
    for (int ni = 0; ni < 4; ++ni)
#pragma unroll
      for (int j = 0; j < 4; ++j) {
        int r = g * 4 + j, c = ni * 16 + m16;
        *(unsigned short*)(wbuf + r * 128 + ((2 * c) ^ ((r & 7) << 4))) =
            f2bf(acc[mi][ni][j]);
      }
    asm volatile("s_waitcnt lgkmcnt(0)" ::: "memory");
    __builtin_amdgcn_sched_barrier(0);
#pragma unroll
    for (int s = 0; s < 2; ++s) {
      int cid = l + 64 * s;
      int r2 = cid >> 3, gi = cid & 7;
      short8 v = *(const short8*)(wbuf + r2 * 128 + gi * 16);
      *(short8*)(dst + (size_t)(mi * 16 + r2) * 128 + gi * 16) = v;
    }
  }
}

// ============================================================
// fc2: out = lrelu(O @ W2 + b2) + feat ; qk-clone + counted WAITVL
// grid 256: mtF = bid>>1 (128 row-tiles), ntF = bid&1 (2 col-tiles)
// ============================================================
__global__ __launch_bounds__(256, 2) void fc2_kernel(
    const char* __restrict__ ws, const float* __restrict__ feat,
    const float* __restrict__ b2, float* __restrict__ out) {
  __shared__ char smem[65536];  // A dbuf 2x16KB @0, B dbuf 2x16KB @32768
  const int tid = threadIdx.x;
  const int mtF = blockIdx.x >> 1, ntF = blockIdx.x & 1;
  const int l = tid & 63, w = tid >> 6;
  const int g = l >> 4, m16 = l & 15;
  const int fxor = (m16 & 7) << 4;
  const char* At = ws + O_OFF + (size_t)mtF * 131072;
  const char* Bt = ws + W2T_OFF + (size_t)ntF * 131072;

  auto stage = [&](int buf, int kt) {
#pragma unroll
    for (int j = 0; j < 4; ++j) {
      int idx = j * 256 + tid;
      glds16(At + (size_t)kt * 16384 + idx * 16, smem + buf * 16384 + idx * 16);
      glds16(Bt + (size_t)kt * 16384 + idx * 16,
             smem + 32768 + buf * 16384 + idx * 16);
    }
  };

  const int mr = (w >> 1) * 64, nr = (w & 1) * 64;
  const f32x4 fz = {0.f, 0.f, 0.f, 0.f};
  f32x4 acc[4][4];
#pragma unroll
  for (int i = 0; i < 4; ++i)
#pragma unroll
    for (int j = 0; j < 4; ++j) acc[i][j] = fz;

  stage(0, 0);
#pragma unroll 1
  for (int kt = 0; kt < 8; ++kt) {
    if (kt < 7) {
      stage((kt + 1) & 1, kt + 1);
      WAITVL(8);
    } else {
      WAITVL(0);
    }
    BAR_SYNC();
    const char* Ab = smem + (kt & 1) * 16384;
    const char* Bb = smem + 32768 + (kt & 1) * 16384;
#pragma unroll
    for (int ks = 0; ks < 2; ++ks) {
      int off = (16 * g + 64 * ks) ^ fxor;
      short8 af[4], bf[4];
#pragma unroll
      for (int i = 0; i < 4; ++i)
        af[i] = *(const short8*)(Ab + (mr + i * 16 + m16) * 128 + off);
#pragma unroll
      for (int i = 0; i < 4; ++i)
        bf[i] = *(const short8*)(Bb + (nr + i * 16 + m16) * 128 + off);
#pragma unroll
      for (int mi = 0; mi < 4; ++mi)
#pragma unroll
        for (int ni = 0; ni < 4; ++ni)
          acc[mi][ni] = mfma16(af[mi], bf[ni], acc[mi][ni]);
    }
    BAR_LGKM();
  }

  // ---- epilogue: bias + leakyrelu + residual, f32 stores ----
#pragma unroll
  for (int mi = 0; mi < 4; ++mi)
#pragma unroll
    for (int ni = 0; ni < 4; ++ni) {
      int d = ntF * 128 + nr + ni * 16 + m16;
      float bias = b2[d];
#pragma unroll
      for (int j = 0; j < 4; ++j) {
        size_t m = (size_t)mtF * 128 + mr + mi * 16 + g * 4 + j;
        float v = acc[mi][ni][j] + bias;
        v = v > 0.f ? v : 0.2f * v;
        out[m * 256 + d] = v + feat[m * 256 + d];
      }
    }
}

// ============================================================
extern "C" void kernel_launch(void* const* d_in, const int* in_sizes, int n_in,
                              void* d_out, int out_size, void* d_ws, size_t ws_size,
                              hipStream_t stream) {
  const float* feat = (const float*)d_in[0];
  const float* Wq = (const float*)d_in[1];
  const float* Wk = (const float*)d_in[2];
  const float* Wv = (const float*)d_in[3];
  const float* W2 = (const float*)d_in[4];
  const float* b2 = (const float*)d_in[5];
  float* out = (float*)d_out;
  char* ws = (char*)d_ws;
  (void)in_sizes; (void)n_in; (void)out_size;

  prep_kernel<<<4096, 256, 0, stream>>>(feat, Wq, Wk, Wv, W2, ws);
  proj_kernel<<<1536, 256, 0, stream>>>(ws);

  const size_t per_batch = 8388608ul;  // S/P: 2048 rows * 4096 B
  int nb = 8;
  while (nb > 1 && S_OFF + (size_t)nb * per_batch > ws_size) nb >>= 1;
  char* Sb = ws + S_OFF;
  float* rs = (float*)(ws + RS_OFF);
  for (int b0 = 0; b0 < 8; b0 += nb) {
    qk_kernel<<<256 * nb, 256, 0, stream>>>(ws, Sb, nb, b0);
    stats_kernel<<<128 * nb, 256, 0, stream>>>(Sb, rs, nb, b0);
    pv_kernel<<<64 * nb, 256, 0, stream>>>(ws, Sb, nb, b0);
  }
  fc2_kernel<<<256, 256, 0, stream>>>(ws, feat, b2, out);
}